// Round 1
// baseline (1315.461 us; speedup 1.0000x reference)
//
#include <hip/hip_runtime.h>

#define NN 100000
#define NE 1600000
// IN=128, HID=128, OUT=64, ED=16

__device__ __forceinline__ float wave_max(float v){
  #pragma unroll
  for (int o = 32; o; o >>= 1) v = fmaxf(v, __shfl_xor(v, o, 64));
  return v;
}
__device__ __forceinline__ float wave_sum(float v){
  #pragma unroll
  for (int o = 32; o; o >>= 1) v += __shfl_xor(v, o, 64);
  return v;
}

// ---- K0: wv[0:16]=We2@ae2, wv[16:32]=Wemu@aemu, wv[32:48]=Wels@aels ----
__global__ void wvec_kernel(const float* __restrict__ We2, const float* __restrict__ ae2,
                            const float* __restrict__ Wemu, const float* __restrict__ aemu,
                            const float* __restrict__ Wels, const float* __restrict__ aels,
                            float* __restrict__ wv){
  int t = threadIdx.x;
  if (t < 16){
    float s = 0.f; for (int c = 0; c < 128; c++) s += We2[t*128+c]*ae2[c];
    wv[t] = s;
  } else if (t < 32){
    int k = t-16; float s = 0.f; for (int c = 0; c < 64; c++) s += Wemu[k*64+c]*aemu[c];
    wv[16+k] = s;
  } else if (t < 48){
    int k = t-32; float s = 0.f; for (int c = 0; c < 64; c++) s += Wels[k*64+c]*aels[c];
    wv[32+k] = s;
  }
}

// ---- K1: per-edge attention scalars ----
__global__ void edge_scalar_kernel(const float* __restrict__ ea, const float* __restrict__ wv,
                                   float* __restrict__ ew2, float* __restrict__ ewmu,
                                   float* __restrict__ ewls){
  int e = blockIdx.x*256 + threadIdx.x;
  if (e >= NE) return;
  const float4* p = (const float4*)(ea + (size_t)e*16);
  float a[16];
  float4 v;
  v = p[0]; a[0]=v.x; a[1]=v.y; a[2]=v.z; a[3]=v.w;
  v = p[1]; a[4]=v.x; a[5]=v.y; a[6]=v.z; a[7]=v.w;
  v = p[2]; a[8]=v.x; a[9]=v.y; a[10]=v.z; a[11]=v.w;
  v = p[3]; a[12]=v.x; a[13]=v.y; a[14]=v.z; a[15]=v.w;
  float s2 = 0.f, smu = 0.f, sls = 0.f;
  #pragma unroll
  for (int k = 0; k < 16; k++){
    s2  = fmaf(a[k], wv[k],    s2);
    smu = fmaf(a[k], wv[16+k], smu);
    sls = fmaf(a[k], wv[32+k], sls);
  }
  ew2[e] = s2; ewmu[e] = smu; ewls[e] = sls;
}

__global__ void zero_kernel(int* __restrict__ p, int n){
  int i = blockIdx.x*256 + threadIdx.x;
  if (i < n) p[i] = 0;
}

__global__ void count_kernel(const int* __restrict__ ei, int* __restrict__ cnt){
  int e = blockIdx.x*256 + threadIdx.x;
  if (e >= NE) return;
  atomicAdd(&cnt[ei[NE + e]], 1);
}

__global__ void scan_kernel(const int* __restrict__ cnt, int* __restrict__ rowptr){
  __shared__ int sums[1024];
  int t = threadIdx.x;
  const int CH = (NN + 1023) >> 10; // 98
  int base = t * CH;
  int s = 0;
  for (int i = 0; i < CH; i++){ int idx = base + i; if (idx < NN) s += cnt[idx]; }
  sums[t] = s; __syncthreads();
  for (int off = 1; off < 1024; off <<= 1){
    int v = (t >= off) ? sums[t-off] : 0;
    __syncthreads();
    sums[t] += v;
    __syncthreads();
  }
  int run = (t == 0) ? 0 : sums[t-1];
  for (int i = 0; i < CH; i++){
    int idx = base + i;
    if (idx < NN){ rowptr[idx] = run; run += cnt[idx]; }
  }
  if (t == 1023) rowptr[NN] = sums[1023];
}

__global__ void scatter_kernel(const int* __restrict__ ei, const int* __restrict__ rowptr,
                               int* __restrict__ fill, uint2* __restrict__ csr){
  int e = blockIdx.x*256 + threadIdx.x;
  if (e >= NE) return;
  int u = ei[e];
  int v = ei[NE + e];
  int pos = atomicAdd(&fill[v], 1);
  csr[rowptr[v] + pos] = make_uint2((unsigned)u, (unsigned)e);
}

// ---- GEMM: Y[nrows x C] = X[nrows x 128] @ W[128 x C] (+bias) ----
template<int C>
__global__ __launch_bounds__(256) void gemm_kernel(const float* __restrict__ X,
                                                   const float* __restrict__ W,
                                                   const float* __restrict__ bias,
                                                   float* __restrict__ Y, int nrows){
  __shared__ float Xs[64][129];
  __shared__ float Ws[128][64];
  int row0 = blockIdx.x * 64;
  int co   = blockIdx.y * 64;
  int t = threadIdx.x;
  #pragma unroll
  for (int p = 0; p < 8; p++){
    int idx = p*256 + t;
    int r = idx >> 5;
    int k4 = idx & 31;
    float4 v = make_float4(0.f,0.f,0.f,0.f);
    if (row0 + r < nrows) v = *(const float4*)(X + (size_t)(row0+r)*128 + k4*4);
    *(float4*)&Xs[r][k4*4] = v;
  }
  #pragma unroll
  for (int p = 0; p < 8; p++){
    int idx = p*256 + t;
    int k = idx >> 4;
    int c4 = idx & 15;
    *(float4*)&Ws[k][c4*4] = *(const float4*)(W + (size_t)k*C + co + c4*4);
  }
  __syncthreads();
  int tr = t >> 4, tc = t & 15;
  int r0 = tr*4, c0 = tc*4;
  float acc[4][4] = {};
  #pragma unroll 4
  for (int k = 0; k < 128; k++){
    float4 wv = *(float4*)&Ws[k][c0];
    float x0 = Xs[r0+0][k], x1 = Xs[r0+1][k], x2 = Xs[r0+2][k], x3 = Xs[r0+3][k];
    acc[0][0] = fmaf(x0, wv.x, acc[0][0]); acc[0][1] = fmaf(x0, wv.y, acc[0][1]);
    acc[0][2] = fmaf(x0, wv.z, acc[0][2]); acc[0][3] = fmaf(x0, wv.w, acc[0][3]);
    acc[1][0] = fmaf(x1, wv.x, acc[1][0]); acc[1][1] = fmaf(x1, wv.y, acc[1][1]);
    acc[1][2] = fmaf(x1, wv.z, acc[1][2]); acc[1][3] = fmaf(x1, wv.w, acc[1][3]);
    acc[2][0] = fmaf(x2, wv.x, acc[2][0]); acc[2][1] = fmaf(x2, wv.y, acc[2][1]);
    acc[2][2] = fmaf(x2, wv.z, acc[2][2]); acc[2][3] = fmaf(x2, wv.w, acc[2][3]);
    acc[3][0] = fmaf(x3, wv.x, acc[3][0]); acc[3][1] = fmaf(x3, wv.y, acc[3][1]);
    acc[3][2] = fmaf(x3, wv.z, acc[3][2]); acc[3][3] = fmaf(x3, wv.w, acc[3][3]);
  }
  #pragma unroll
  for (int i = 0; i < 4; i++){
    int r = row0 + r0 + i;
    if (r < nrows){
      float b0=0.f,b1=0.f,b2=0.f,b3=0.f;
      if (bias){ b0=bias[co+c0]; b1=bias[co+c0+1]; b2=bias[co+c0+2]; b3=bias[co+c0+3]; }
      float4 o = make_float4(acc[i][0]+b0, acc[i][1]+b1, acc[i][2]+b2, acc[i][3]+b3);
      *(float4*)(Y + (size_t)r*C + co + c0) = o;
    }
  }
}

template<int C>
__global__ __launch_bounds__(256) void dots_kernel(const float* __restrict__ H,
                                                   const float* __restrict__ asrc,
                                                   const float* __restrict__ adst,
                                                   float* __restrict__ s, float* __restrict__ d){
  int wid = (blockIdx.x * blockDim.x + threadIdx.x) >> 6;
  int lane = threadIdx.x & 63;
  if (wid >= NN) return;
  const float* h = H + (size_t)wid * C;
  float ps = 0.f, pd = 0.f;
  #pragma unroll
  for (int c = lane; c < C; c += 64){
    float hv = h[c];
    ps = fmaf(hv, asrc[c], ps);
    pd = fmaf(hv, adst[c], pd);
  }
  ps = wave_sum(ps); pd = wave_sum(pd);
  if (lane == 0){ s[wid] = ps; d[wid] = pd; }
}

template<int C, bool HAS_EW, bool RELU, bool RESID>
__global__ __launch_bounds__(256) void agg_kernel(const float* __restrict__ H,
                                                  const float* __restrict__ s,
                                                  const float* __restrict__ dsc,
                                                  const float* __restrict__ ew,
                                                  const int* __restrict__ rowptr,
                                                  const uint2* __restrict__ csr,
                                                  const float* __restrict__ bias,
                                                  const float* __restrict__ resid,
                                                  float* __restrict__ out){
  int v = (blockIdx.x * blockDim.x + threadIdx.x) >> 6;
  int lane = threadIdx.x & 63;
  if (v >= NN) return;
  int rs = rowptr[v], re = rowptr[v+1];
  int deg = re - rs;
  float d_v = dsc[v];
  float m = -1e30f;
  float ewsum = 0.f;
  for (int base = rs; base < re; base += 64){
    int i = base + lane;
    float logit = -1e30f;
    if (i < re){
      uint2 rec = csr[i];
      float e = HAS_EW ? ew[rec.y] : 0.f;
      ewsum += e;
      float a = s[rec.x] + d_v + e;
      logit = a > 0.f ? a : 0.2f*a;
    }
    m = fmaxf(m, logit);
  }
  m = wave_max(m);
  if (HAS_EW) ewsum = wave_sum(ewsum);
  float selfa = s[v] + d_v + (HAS_EW ? ewsum / (float)(deg > 1 ? deg : 1) : 0.f);
  float lself = selfa > 0.f ? selfa : 0.2f*selfa;
  m = fmaxf(m, lself);
  float psum = 0.f;
  for (int base = rs; base < re; base += 64){
    int i = base + lane;
    if (i < re){
      uint2 rec = csr[i];
      float e = HAS_EW ? ew[rec.y] : 0.f;
      float a = s[rec.x] + d_v + e;
      float logit = a > 0.f ? a : 0.2f*a;
      psum += __expf(logit - m);
    }
  }
  psum = wave_sum(psum) + __expf(lself - m);
  float invsum = 1.f / psum;
  float acc0 = 0.f, acc1 = 0.f;
  {
    float wself = __expf(lself - m) * invsum;
    if constexpr (C == 128){
      float2 hv = *(const float2*)(H + (size_t)v*C + lane*2);
      acc0 = wself*hv.x; acc1 = wself*hv.y;
    } else {
      acc0 = wself * H[(size_t)v*C + lane];
    }
  }
  for (int base = rs; base < re; base += 64){
    int i = base + lane;
    float wgt = 0.f; int u = 0;
    if (i < re){
      uint2 rec = csr[i];
      u = (int)rec.x;
      float e = HAS_EW ? ew[rec.y] : 0.f;
      float a = s[rec.x] + d_v + e;
      float logit = a > 0.f ? a : 0.2f*a;
      wgt = __expf(logit - m) * invsum;
    }
    int nv = re - base; if (nv > 64) nv = 64;
    for (int j = 0; j < nv; j++){
      int   uj = __shfl(u, j, 64);
      float wj = __shfl(wgt, j, 64);
      if constexpr (C == 128){
        float2 hv = *(const float2*)(H + (size_t)uj*C + lane*2);
        acc0 = fmaf(wj, hv.x, acc0);
        acc1 = fmaf(wj, hv.y, acc1);
      } else {
        acc0 = fmaf(wj, H[(size_t)uj*C + lane], acc0);
      }
    }
  }
  if constexpr (C == 128){
    int c0 = lane*2;
    float o0 = acc0 + bias[c0], o1 = acc1 + bias[c0+1];
    if (RELU){ o0 = fmaxf(o0, 0.f); o1 = fmaxf(o1, 0.f); }
    if (RESID){ o0 += resid[(size_t)v*C + c0]; o1 += resid[(size_t)v*C + c0 + 1]; }
    *(float2*)(out + (size_t)v*C + c0) = make_float2(o0, o1);
  } else {
    float o = acc0 + bias[lane];
    if (RELU) o = fmaxf(o, 0.f);
    if (RESID) o += resid[(size_t)v*C + lane];
    out[(size_t)v*C + lane] = o;
  }
}

extern "C" void kernel_launch(void* const* d_in, const int* in_sizes, int n_in,
                              void* d_out, int out_size, void* d_ws, size_t ws_size,
                              hipStream_t stream){
  const float* x    = (const float*)d_in[0];
  const int*   ei   = (const int*)  d_in[1];
  const float* ea   = (const float*)d_in[2];
  const float* W1   = (const float*)d_in[3];
  const float* a1s  = (const float*)d_in[4];
  const float* a1d  = (const float*)d_in[5];
  const float* b1   = (const float*)d_in[6];
  const float* W2   = (const float*)d_in[7];
  const float* a2s  = (const float*)d_in[8];
  const float* a2d  = (const float*)d_in[9];
  const float* b2   = (const float*)d_in[10];
  const float* We2  = (const float*)d_in[11];
  const float* ae2  = (const float*)d_in[12];
  const float* Wr   = (const float*)d_in[13];
  const float* br   = (const float*)d_in[14];
  const float* Wmu  = (const float*)d_in[15];
  const float* amus = (const float*)d_in[16];
  const float* amud = (const float*)d_in[17];
  const float* bmu  = (const float*)d_in[18];
  const float* Wemu = (const float*)d_in[19];
  const float* aemu = (const float*)d_in[20];
  const float* Wls  = (const float*)d_in[21];
  const float* alss = (const float*)d_in[22];
  const float* alsd = (const float*)d_in[23];
  const float* bls  = (const float*)d_in[24];
  const float* Wels = (const float*)d_in[25];
  const float* aels = (const float*)d_in[26];

  char* base = (char*)d_ws;
  size_t off = 0;
  auto alloc = [&](size_t bytes)->char*{
    char* p = base + off;
    off = (off + bytes + 511) & ~(size_t)511;
    return p;
  };
  float* ew2    = (float*)alloc((size_t)NE*4);
  float* ewmu   = (float*)alloc((size_t)NE*4);
  float* ewls   = (float*)alloc((size_t)NE*4);
  int*   rowptr = (int*)  alloc((size_t)(NN+1)*4);
  int*   cnt    = (int*)  alloc((size_t)2*NN*4);   // cnt + fill contiguous
  int*   fill   = cnt + NN;
  uint2* csr    = (uint2*)alloc((size_t)NE*8);
  float* wv     = (float*)alloc(48*4);
  float* sbuf   = (float*)alloc((size_t)NN*4);
  float* dbuf   = (float*)alloc((size_t)NN*4);
  float* bufA   = (float*)alloc((size_t)NN*128*4); // H1, later Hmu
  float* bufB   = (float*)alloc((size_t)NN*128*4); // h1, later h
  float* bufC   = (float*)alloc((size_t)NN*128*4); // H2, later Hls
  if (off > ws_size) return;

  float* outF = (float*)d_out;          // XR scratch, then [mu | logstd]
  float* muO  = outF;
  float* lsO  = outF + (size_t)NN*64;

  const int EB = (NE + 255)/256;
  const int WB = (NN*64 + 255)/256;     // one wave per node, 4 per block
  const int GB = (NN + 63)/64;

  wvec_kernel<<<1, 64, 0, stream>>>(We2, ae2, Wemu, aemu, Wels, aels, wv);
  edge_scalar_kernel<<<EB, 256, 0, stream>>>(ea, wv, ew2, ewmu, ewls);
  zero_kernel<<<(2*NN + 255)/256, 256, 0, stream>>>(cnt, 2*NN);
  count_kernel<<<EB, 256, 0, stream>>>(ei, cnt);
  scan_kernel<<<1, 1024, 0, stream>>>(cnt, rowptr);
  scatter_kernel<<<EB, 256, 0, stream>>>(ei, rowptr, fill, csr);

  // conv1: h1 = relu(agg(x@W1) + b1)
  gemm_kernel<128><<<dim3(GB, 2), 256, 0, stream>>>(x, W1, nullptr, bufA, NN);
  dots_kernel<128><<<WB, 256, 0, stream>>>(bufA, a1s, a1d, sbuf, dbuf);
  agg_kernel<128,false,true,false><<<WB, 256, 0, stream>>>(bufA, sbuf, dbuf, nullptr,
                                                           rowptr, csr, b1, nullptr, bufB);
  // conv2: h = relu(agg(h1@W2, ew2) + b2) + (x@Wr + br)
  gemm_kernel<128><<<dim3(GB, 2), 256, 0, stream>>>(bufB, W2, nullptr, bufC, NN);
  dots_kernel<128><<<WB, 256, 0, stream>>>(bufC, a2s, a2d, sbuf, dbuf);
  gemm_kernel<128><<<dim3(GB, 2), 256, 0, stream>>>(x, Wr, br, outF, NN); // XR -> d_out
  agg_kernel<128,true,true,true><<<WB, 256, 0, stream>>>(bufC, sbuf, dbuf, ew2,
                                                         rowptr, csr, b2, outF, bufB);
  // mu
  gemm_kernel<64><<<dim3(GB, 1), 256, 0, stream>>>(bufB, Wmu, nullptr, bufA, NN);
  dots_kernel<64><<<WB, 256, 0, stream>>>(bufA, amus, amud, sbuf, dbuf);
  agg_kernel<64,true,false,false><<<WB, 256, 0, stream>>>(bufA, sbuf, dbuf, ewmu,
                                                          rowptr, csr, bmu, nullptr, muO);
  // logstd
  gemm_kernel<64><<<dim3(GB, 1), 256, 0, stream>>>(bufB, Wls, nullptr, bufC, NN);
  dots_kernel<64><<<WB, 256, 0, stream>>>(bufC, alss, alsd, sbuf, dbuf);
  agg_kernel<64,true,false,false><<<WB, 256, 0, stream>>>(bufC, sbuf, dbuf, ewls,
                                                          rowptr, csr, bls, nullptr, lsO);
}

// Round 2
// 957.864 us; speedup vs baseline: 1.3733x; 1.3733x over previous
//
#include <hip/hip_runtime.h>

#define NN 100000
#define NE 1600000
#define NB ((NN + 255) / 256)   // 391 blocks for per-block scan

__device__ __forceinline__ float wave_max(float v){
  #pragma unroll
  for (int o = 32; o; o >>= 1) v = fmaxf(v, __shfl_xor(v, o, 64));
  return v;
}
__device__ __forceinline__ float wave_sum(float v){
  #pragma unroll
  for (int o = 32; o; o >>= 1) v += __shfl_xor(v, o, 64);
  return v;
}
__device__ __forceinline__ int wave_sum_i(int v){
  #pragma unroll
  for (int o = 32; o; o >>= 1) v += __shfl_xor(v, o, 64);
  return v;
}
__device__ __forceinline__ float bf2f(unsigned short x){
  return __uint_as_float(((unsigned)x) << 16);
}
__device__ __forceinline__ unsigned short f2bf(float f){
  unsigned u = __float_as_uint(f);
  return (unsigned short)((u + 0x7FFFu + ((u >> 16) & 1u)) >> 16);
}

// ---- wv[0:16]=We2@ae2, wv[16:32]=Wemu@aemu, wv[32:48]=Wels@aels ----
__global__ void wvec_kernel(const float* __restrict__ We2, const float* __restrict__ ae2,
                            const float* __restrict__ Wemu, const float* __restrict__ aemu,
                            const float* __restrict__ Wels, const float* __restrict__ aels,
                            float* __restrict__ wv){
  int t = threadIdx.x;
  if (t < 16){
    float s = 0.f; for (int c = 0; c < 128; c++) s += We2[t*128+c]*ae2[c];
    wv[t] = s;
  } else if (t < 32){
    int k = t-16; float s = 0.f; for (int c = 0; c < 64; c++) s += Wemu[k*64+c]*aemu[c];
    wv[16+k] = s;
  } else if (t < 48){
    int k = t-32; float s = 0.f; for (int c = 0; c < 64; c++) s += Wels[k*64+c]*aels[c];
    wv[32+k] = s;
  }
}

// ---- per-edge attention scalars ----
__global__ void edge_scalar_kernel(const float* __restrict__ ea, const float* __restrict__ wv,
                                   float* __restrict__ ew2, float* __restrict__ ewmu,
                                   float* __restrict__ ewls){
  int e = blockIdx.x*256 + threadIdx.x;
  if (e >= NE) return;
  const float4* p = (const float4*)(ea + (size_t)e*16);
  float a[16];
  float4 v;
  v = p[0]; a[0]=v.x; a[1]=v.y; a[2]=v.z; a[3]=v.w;
  v = p[1]; a[4]=v.x; a[5]=v.y; a[6]=v.z; a[7]=v.w;
  v = p[2]; a[8]=v.x; a[9]=v.y; a[10]=v.z; a[11]=v.w;
  v = p[3]; a[12]=v.x; a[13]=v.y; a[14]=v.z; a[15]=v.w;
  float s2 = 0.f, smu = 0.f, sls = 0.f;
  #pragma unroll
  for (int k = 0; k < 16; k++){
    s2  = fmaf(a[k], wv[k],    s2);
    smu = fmaf(a[k], wv[16+k], smu);
    sls = fmaf(a[k], wv[32+k], sls);
  }
  ew2[e] = s2; ewmu[e] = smu; ewls[e] = sls;
}

__global__ void zero_kernel(int* __restrict__ p, int n){
  int i = blockIdx.x*256 + threadIdx.x;
  if (i < n) p[i] = 0;
}

__global__ void count_kernel(const int* __restrict__ ei, int* __restrict__ cnt){
  int e = blockIdx.x*256 + threadIdx.x;
  if (e >= NE) return;
  atomicAdd(&cnt[ei[NE + e]], 1);
}

// ---- multi-block exclusive scan: bsum -> bscan -> rowptr ----
__global__ void bsum_kernel(const int* __restrict__ cnt, int* __restrict__ bsum){
  int i = blockIdx.x*256 + threadIdx.x;
  int v = (i < NN) ? cnt[i] : 0;
  v = wave_sum_i(v);
  __shared__ int sh[4];
  if ((threadIdx.x & 63) == 0) sh[threadIdx.x >> 6] = v;
  __syncthreads();
  if (threadIdx.x == 0) bsum[blockIdx.x] = sh[0]+sh[1]+sh[2]+sh[3];
}

__global__ void bscan_kernel(int* __restrict__ bsum, int* __restrict__ rowptr){
  __shared__ int sh[512];
  int t = threadIdx.x;
  int v = (t < NB) ? bsum[t] : 0;
  sh[t] = v; __syncthreads();
  for (int o = 1; o < 512; o <<= 1){
    int add = (t >= o) ? sh[t-o] : 0;
    __syncthreads();
    sh[t] += add;
    __syncthreads();
  }
  if (t < NB) bsum[t] = sh[t] - v;   // exclusive block offsets
  if (t == 0) rowptr[NN] = NE;
}

__global__ void rowptr_kernel(const int* __restrict__ cnt, const int* __restrict__ bex,
                              int* __restrict__ rowptr){
  __shared__ int sh[256];
  int t = threadIdx.x;
  int i = blockIdx.x*256 + t;
  int v = (i < NN) ? cnt[i] : 0;
  sh[t] = v; __syncthreads();
  for (int o = 1; o < 256; o <<= 1){
    int add = (t >= o) ? sh[t-o] : 0;
    __syncthreads();
    sh[t] += add;
    __syncthreads();
  }
  if (i < NN) rowptr[i] = bex[blockIdx.x] + sh[t] - v;  // exclusive
}

__global__ void scatter_kernel(const int* __restrict__ ei, const int* __restrict__ rowptr,
                               int* __restrict__ fill, uint2* __restrict__ csr){
  int e = blockIdx.x*256 + threadIdx.x;
  if (e >= NE) return;
  int u = ei[e];
  int v = ei[NE + e];
  int pos = atomicAdd(&fill[v], 1);
  csr[rowptr[v] + pos] = make_uint2((unsigned)u, (unsigned)e);
}

// ---- GEMM: Y[nrows x C] = X[nrows x 128] @ W[128 x C] (+bias)
//      OUTBF: write bf16 (ushort). DOTS: fused s/d = Y.asrc, Y.adst via atomics.
__device__ __forceinline__ void fma_row(float acc[4][4], int r, float x, float4 w){
  acc[r][0] = fmaf(x, w.x, acc[r][0]);
  acc[r][1] = fmaf(x, w.y, acc[r][1]);
  acc[r][2] = fmaf(x, w.z, acc[r][2]);
  acc[r][3] = fmaf(x, w.w, acc[r][3]);
}

template<int C, bool DOTS, bool OUTBF>
__global__ __launch_bounds__(256) void gemm_kernel(const float* __restrict__ X,
                                                   const float* __restrict__ W,
                                                   const float* __restrict__ bias,
                                                   void* __restrict__ Yv, int nrows,
                                                   const float* __restrict__ asrc,
                                                   const float* __restrict__ adst,
                                                   float* __restrict__ sg,
                                                   float* __restrict__ dg){
  __shared__ float Xs[64][132];   // padded for float4-aligned k-reads
  __shared__ float Ws[128][64];
  int row0 = blockIdx.x * 64;
  int co   = blockIdx.y * 64;
  int t = threadIdx.x;
  #pragma unroll
  for (int p = 0; p < 8; p++){
    int idx = p*256 + t;
    int r = idx >> 5;
    int k4 = idx & 31;
    float4 v = make_float4(0.f,0.f,0.f,0.f);
    if (row0 + r < nrows) v = *(const float4*)(X + (size_t)(row0+r)*128 + k4*4);
    *(float4*)&Xs[r][k4*4] = v;
  }
  #pragma unroll
  for (int p = 0; p < 8; p++){
    int idx = p*256 + t;
    int k = idx >> 4;
    int c4 = idx & 15;
    *(float4*)&Ws[k][c4*4] = *(const float4*)(W + (size_t)k*C + co + c4*4);
  }
  __syncthreads();
  int tr = t >> 4, tc = t & 15;
  int r0 = tr*4, c0 = tc*4;
  float acc[4][4] = {};
  #pragma unroll 4
  for (int k = 0; k < 128; k += 4){
    float4 xa = *(float4*)&Xs[r0+0][k];
    float4 xb = *(float4*)&Xs[r0+1][k];
    float4 xc = *(float4*)&Xs[r0+2][k];
    float4 xd = *(float4*)&Xs[r0+3][k];
    float4 w0 = *(float4*)&Ws[k+0][c0];
    float4 w1 = *(float4*)&Ws[k+1][c0];
    float4 w2 = *(float4*)&Ws[k+2][c0];
    float4 w3 = *(float4*)&Ws[k+3][c0];
    fma_row(acc,0,xa.x,w0); fma_row(acc,1,xb.x,w0); fma_row(acc,2,xc.x,w0); fma_row(acc,3,xd.x,w0);
    fma_row(acc,0,xa.y,w1); fma_row(acc,1,xb.y,w1); fma_row(acc,2,xc.y,w1); fma_row(acc,3,xd.y,w1);
    fma_row(acc,0,xa.z,w2); fma_row(acc,1,xb.z,w2); fma_row(acc,2,xc.z,w2); fma_row(acc,3,xd.z,w2);
    fma_row(acc,0,xa.w,w3); fma_row(acc,1,xb.w,w3); fma_row(acc,2,xc.w,w3); fma_row(acc,3,xd.w,w3);
  }
  // fused attention dots from fp32 accumulators
  if constexpr (DOTS){
    float as0 = asrc[co+c0], as1 = asrc[co+c0+1], as2 = asrc[co+c0+2], as3 = asrc[co+c0+3];
    float ad0 = adst[co+c0], ad1 = adst[co+c0+1], ad2 = adst[co+c0+2], ad3 = adst[co+c0+3];
    #pragma unroll
    for (int i = 0; i < 4; i++){
      float ps = acc[i][0]*as0 + acc[i][1]*as1 + acc[i][2]*as2 + acc[i][3]*as3;
      float pd = acc[i][0]*ad0 + acc[i][1]*ad1 + acc[i][2]*ad2 + acc[i][3]*ad3;
      #pragma unroll
      for (int o = 8; o; o >>= 1){
        ps += __shfl_xor(ps, o, 64);
        pd += __shfl_xor(pd, o, 64);
      }
      int r = row0 + r0 + i;
      if (tc == 0 && r < nrows){
        atomicAdd(&sg[r], ps);
        atomicAdd(&dg[r], pd);
      }
    }
  }
  #pragma unroll
  for (int i = 0; i < 4; i++){
    int r = row0 + r0 + i;
    if (r < nrows){
      float b0=0.f,b1=0.f,b2=0.f,b3=0.f;
      if (bias){ b0=bias[co+c0]; b1=bias[co+c0+1]; b2=bias[co+c0+2]; b3=bias[co+c0+3]; }
      float o0 = acc[i][0]+b0, o1 = acc[i][1]+b1, o2 = acc[i][2]+b2, o3 = acc[i][3]+b3;
      if constexpr (OUTBF){
        ushort4 o4;
        o4.x = f2bf(o0); o4.y = f2bf(o1); o4.z = f2bf(o2); o4.w = f2bf(o3);
        *(ushort4*)((unsigned short*)Yv + (size_t)r*C + co + c0) = o4;
      } else {
        *(float4*)((float*)Yv + (size_t)r*C + co + c0) = make_float4(o0,o1,o2,o3);
      }
    }
  }
}

// ---- single-pass online-softmax aggregation, bf16 H ----
template<int C, bool HAS_EW, bool RELU, bool RESID>
__global__ __launch_bounds__(256) void agg_kernel(const unsigned short* __restrict__ Hb,
                                                  const float* __restrict__ s,
                                                  const float* __restrict__ dsc,
                                                  const float* __restrict__ ew,
                                                  const int* __restrict__ rowptr,
                                                  const uint2* __restrict__ csr,
                                                  const float* __restrict__ bias,
                                                  const float* __restrict__ resid,
                                                  float* __restrict__ out){
  int v = (blockIdx.x * blockDim.x + threadIdx.x) >> 6;
  int lane = threadIdx.x & 63;
  if (v >= NN) return;
  int rs = rowptr[v], re = rowptr[v+1];
  int deg = re - rs;
  float d_v = dsc[v];
  float m = -1e30f, p = 0.f, acc0 = 0.f, acc1 = 0.f, ewp = 0.f;
  for (int base = rs; base < re; base += 64){
    int i = base + lane;
    float l = -1e30f; int u = 0; float w;
    if (i < re){
      uint2 rec = csr[i];
      u = (int)rec.x;
      float e = HAS_EW ? ew[rec.y] : 0.f;
      if (HAS_EW) ewp += e;
      float a = s[u] + d_v + e;
      l = a > 0.f ? a : 0.2f*a;
    }
    float cm = wave_max(l);
    if (cm > m){
      float sc = __expf(m - cm);
      p *= sc; acc0 *= sc; acc1 *= sc;
      m = cm;
    }
    w = __expf(l - m);          // masked lanes: exp(-huge)=0
    p += wave_sum(w);
    int nv = re - base; if (nv > 64) nv = 64;
    for (int j = 0; j < nv; j++){
      int   uj = __shfl(u, j, 64);
      float wj = __shfl(w, j, 64);
      if constexpr (C == 128){
        ushort2 q = *(const ushort2*)(Hb + (size_t)uj*128 + lane*2);
        acc0 = fmaf(wj, bf2f(q.x), acc0);
        acc1 = fmaf(wj, bf2f(q.y), acc1);
      } else {
        acc0 = fmaf(wj, bf2f(Hb[(size_t)uj*64 + lane]), acc0);
      }
    }
  }
  if (HAS_EW) ewp = wave_sum(ewp);
  float selfa = s[v] + d_v + (HAS_EW ? ewp / (float)(deg > 1 ? deg : 1) : 0.f);
  float lself = selfa > 0.f ? selfa : 0.2f*selfa;
  if (lself > m){
    float sc = __expf(m - lself);
    p *= sc; acc0 *= sc; acc1 *= sc;
    m = lself;
  }
  float wself = __expf(lself - m);
  p += wself;
  if constexpr (C == 128){
    ushort2 q = *(const ushort2*)(Hb + (size_t)v*128 + lane*2);
    acc0 = fmaf(wself, bf2f(q.x), acc0);
    acc1 = fmaf(wself, bf2f(q.y), acc1);
  } else {
    acc0 = fmaf(wself, bf2f(Hb[(size_t)v*64 + lane]), acc0);
  }
  float inv = 1.f / p;
  if constexpr (C == 128){
    int c0 = lane*2;
    float o0 = acc0*inv + bias[c0], o1 = acc1*inv + bias[c0+1];
    if (RELU){ o0 = fmaxf(o0, 0.f); o1 = fmaxf(o1, 0.f); }
    if (RESID){ o0 += resid[(size_t)v*C + c0]; o1 += resid[(size_t)v*C + c0 + 1]; }
    *(float2*)(out + (size_t)v*C + c0) = make_float2(o0, o1);
  } else {
    float o = acc0*inv + bias[lane];
    if (RELU) o = fmaxf(o, 0.f);
    if (RESID) o += resid[(size_t)v*C + lane];
    out[(size_t)v*C + lane] = o;
  }
}

extern "C" void kernel_launch(void* const* d_in, const int* in_sizes, int n_in,
                              void* d_out, int out_size, void* d_ws, size_t ws_size,
                              hipStream_t stream){
  const float* x    = (const float*)d_in[0];
  const int*   ei   = (const int*)  d_in[1];
  const float* ea   = (const float*)d_in[2];
  const float* W1   = (const float*)d_in[3];
  const float* a1s  = (const float*)d_in[4];
  const float* a1d  = (const float*)d_in[5];
  const float* b1   = (const float*)d_in[6];
  const float* W2   = (const float*)d_in[7];
  const float* a2s  = (const float*)d_in[8];
  const float* a2d  = (const float*)d_in[9];
  const float* b2   = (const float*)d_in[10];
  const float* We2  = (const float*)d_in[11];
  const float* ae2  = (const float*)d_in[12];
  const float* Wr   = (const float*)d_in[13];
  const float* br   = (const float*)d_in[14];
  const float* Wmu  = (const float*)d_in[15];
  const float* amus = (const float*)d_in[16];
  const float* amud = (const float*)d_in[17];
  const float* bmu  = (const float*)d_in[18];
  const float* Wemu = (const float*)d_in[19];
  const float* aemu = (const float*)d_in[20];
  const float* Wls  = (const float*)d_in[21];
  const float* alss = (const float*)d_in[22];
  const float* alsd = (const float*)d_in[23];
  const float* bls  = (const float*)d_in[24];
  const float* Wels = (const float*)d_in[25];
  const float* aels = (const float*)d_in[26];

  char* base = (char*)d_ws;
  size_t off = 0;
  auto alloc = [&](size_t bytes)->char*{
    char* p = base + off;
    off = (off + bytes + 511) & ~(size_t)511;
    return p;
  };
  float* ew2    = (float*)alloc((size_t)NE*4);
  float* ewmu   = (float*)alloc((size_t)NE*4);
  float* ewls   = (float*)alloc((size_t)NE*4);
  int*   rowptr = (int*)  alloc((size_t)(NN+1)*4);
  int*   cnt    = (int*)  alloc((size_t)2*NN*4);   // cnt + fill contiguous
  int*   fill   = cnt + NN;
  int*   bsum   = (int*)  alloc(512*4);
  uint2* csr    = (uint2*)alloc((size_t)NE*8);
  float* wv     = (float*)alloc(48*4);
  float* sbuf   = (float*)alloc((size_t)2*NN*4);   // s + d contiguous
  float* dbuf   = sbuf + NN;
  unsigned short* bufA = (unsigned short*)alloc((size_t)NN*128*2); // H1 / Hmu (bf16)
  unsigned short* bufC = (unsigned short*)alloc((size_t)NN*128*2); // H2 / Hls (bf16)
  float* bufB   = (float*)alloc((size_t)NN*128*4); // h1, then h (fp32, GEMM input)
  if (off > ws_size) return;

  float* outF = (float*)d_out;          // XR scratch, then [mu | logstd]
  float* muO  = outF;
  float* lsO  = outF + (size_t)NN*64;

  const int EB = (NE + 255)/256;
  const int WB = (NN*64 + 255)/256;     // one wave per node, 4 per block
  const int GB = (NN + 63)/64;

  // precompute + graph build
  wvec_kernel<<<1, 64, 0, stream>>>(We2, ae2, Wemu, aemu, Wels, aels, wv);
  edge_scalar_kernel<<<EB, 256, 0, stream>>>(ea, wv, ew2, ewmu, ewls);
  zero_kernel<<<(2*NN + 255)/256, 256, 0, stream>>>(cnt, 2*NN);
  count_kernel<<<EB, 256, 0, stream>>>(ei, cnt);
  bsum_kernel<<<NB, 256, 0, stream>>>(cnt, bsum);
  bscan_kernel<<<1, 512, 0, stream>>>(bsum, rowptr);
  rowptr_kernel<<<NB, 256, 0, stream>>>(cnt, bsum, rowptr);
  scatter_kernel<<<EB, 256, 0, stream>>>(ei, rowptr, fill, csr);

  // conv1: h1 = relu(agg(x@W1) + b1)
  zero_kernel<<<(2*NN + 255)/256, 256, 0, stream>>>((int*)sbuf, 2*NN);
  gemm_kernel<128,true,true><<<dim3(GB,2), 256, 0, stream>>>(x, W1, nullptr, bufA, NN,
                                                             a1s, a1d, sbuf, dbuf);
  agg_kernel<128,false,true,false><<<WB, 256, 0, stream>>>(bufA, sbuf, dbuf, nullptr,
                                                           rowptr, csr, b1, nullptr, bufB);
  // conv2: h = relu(agg(h1@W2, ew2) + b2) + (x@Wr + br)
  zero_kernel<<<(2*NN + 255)/256, 256, 0, stream>>>((int*)sbuf, 2*NN);
  gemm_kernel<128,true,true><<<dim3(GB,2), 256, 0, stream>>>(bufB, W2, nullptr, bufC, NN,
                                                             a2s, a2d, sbuf, dbuf);
  gemm_kernel<128,false,false><<<dim3(GB,2), 256, 0, stream>>>(x, Wr, br, outF, NN,
                                                               nullptr, nullptr, nullptr, nullptr);
  agg_kernel<128,true,true,true><<<WB, 256, 0, stream>>>(bufC, sbuf, dbuf, ew2,
                                                         rowptr, csr, b2, outF, bufB);
  // mu
  zero_kernel<<<(2*NN + 255)/256, 256, 0, stream>>>((int*)sbuf, 2*NN);
  gemm_kernel<64,true,true><<<dim3(GB,1), 256, 0, stream>>>(bufB, Wmu, nullptr, bufA, NN,
                                                            amus, amud, sbuf, dbuf);
  agg_kernel<64,true,false,false><<<WB, 256, 0, stream>>>(bufA, sbuf, dbuf, ewmu,
                                                          rowptr, csr, bmu, nullptr, muO);
  // logstd
  zero_kernel<<<(2*NN + 255)/256, 256, 0, stream>>>((int*)sbuf, 2*NN);
  gemm_kernel<64,true,true><<<dim3(GB,1), 256, 0, stream>>>(bufB, Wls, nullptr, bufC, NN,
                                                            alss, alsd, sbuf, dbuf);
  agg_kernel<64,true,false,false><<<WB, 256, 0, stream>>>(bufC, sbuf, dbuf, ewls,
                                                          rowptr, csr, bls, nullptr, lsO);
}

// Round 3
// 626.213 us; speedup vs baseline: 2.1007x; 1.5296x over previous
//
#include <hip/hip_runtime.h>

#define NN 100000
#define NE 1600000
#define NB ((NN + 255) / 256)   // 391

typedef __attribute__((ext_vector_type(8))) short bf16x8;
typedef __attribute__((ext_vector_type(4))) float f32x4;

__device__ __forceinline__ float wave_sum(float v){
  #pragma unroll
  for (int o = 32; o; o >>= 1) v += __shfl_xor(v, o, 64);
  return v;
}
__device__ __forceinline__ int wave_sum_i(int v){
  #pragma unroll
  for (int o = 32; o; o >>= 1) v += __shfl_xor(v, o, 64);
  return v;
}
__device__ __forceinline__ float bf2f(unsigned short x){
  return __uint_as_float(((unsigned)x) << 16);
}
__device__ __forceinline__ unsigned short f2bf(float f){
  unsigned u = __float_as_uint(f);
  return (unsigned short)((u + 0x7FFFu + ((u >> 16) & 1u)) >> 16);
}
__device__ __forceinline__ float rl_f(float v, int j){
  return __uint_as_float(__builtin_amdgcn_readlane(__float_as_uint(v), j));
}

// ---- weight prep: transpose + bf16 cast. b3 = [Wmu | Wls] concat ----
__global__ void prep_w_kernel(const float* __restrict__ W1, const float* __restrict__ W2,
                              const float* __restrict__ Wr, const float* __restrict__ Wmu,
                              const float* __restrict__ Wls,
                              unsigned short* __restrict__ W1t, unsigned short* __restrict__ W2t,
                              unsigned short* __restrict__ Wrt, unsigned short* __restrict__ Wmlt){
  int b = blockIdx.x, t = threadIdx.x;
  for (int it = 0; it < 64; it++){
    int idx = it*256 + t;          // 16384 entries
    int k = idx >> 7, c = idx & 127;
    float v; unsigned short* dst;
    if (b == 0){ v = W1[k*128+c]; dst = W1t; }
    else if (b == 1){ v = W2[k*128+c]; dst = W2t; }
    else if (b == 2){ v = Wr[k*128+c]; dst = Wrt; }
    else { v = (c < 64) ? Wmu[k*64+c] : Wls[k*64+(c-64)]; dst = Wmlt; }
    dst[c*128 + k] = f2bf(v);      // [col][k]
  }
}

__global__ void wvec_kernel(const float* __restrict__ We2, const float* __restrict__ ae2,
                            const float* __restrict__ Wemu, const float* __restrict__ aemu,
                            const float* __restrict__ Wels, const float* __restrict__ aels,
                            float* __restrict__ wv){
  int t = threadIdx.x;
  if (t < 16){
    float s = 0.f; for (int c = 0; c < 128; c++) s += We2[t*128+c]*ae2[c];
    wv[t] = s;
  } else if (t < 32){
    int k = t-16; float s = 0.f; for (int c = 0; c < 64; c++) s += Wemu[k*64+c]*aemu[c];
    wv[16+k] = s;
  } else if (t < 48){
    int k = t-32; float s = 0.f; for (int c = 0; c < 64; c++) s += Wels[k*64+c]*aels[c];
    wv[32+k] = s;
  }
}

__global__ void cast_x_kernel(const float* __restrict__ x, unsigned short* __restrict__ Xb){
  int i = blockIdx.x*256 + threadIdx.x;   // 8 elems each
  if (i >= NN*128/8) return;
  const float4* src = (const float4*)x + (size_t)i*2;
  float4 v0 = src[0], v1 = src[1];
  ushort4 o0 = make_ushort4(f2bf(v0.x), f2bf(v0.y), f2bf(v0.z), f2bf(v0.w));
  ushort4 o1 = make_ushort4(f2bf(v1.x), f2bf(v1.y), f2bf(v1.z), f2bf(v1.w));
  *(ushort4*)(Xb + (size_t)i*8)     = o0;
  *(ushort4*)(Xb + (size_t)i*8 + 4) = o1;
}

// ---- per-edge attention scalars, interleaved by e ----
__global__ void edge_scalar_kernel(const float* __restrict__ ea, const float* __restrict__ wv,
                                   float* __restrict__ ew3){
  int e = blockIdx.x*256 + threadIdx.x;
  if (e >= NE) return;
  const float4* p = (const float4*)(ea + (size_t)e*16);
  float a[16]; float4 v;
  v = p[0]; a[0]=v.x; a[1]=v.y; a[2]=v.z; a[3]=v.w;
  v = p[1]; a[4]=v.x; a[5]=v.y; a[6]=v.z; a[7]=v.w;
  v = p[2]; a[8]=v.x; a[9]=v.y; a[10]=v.z; a[11]=v.w;
  v = p[3]; a[12]=v.x; a[13]=v.y; a[14]=v.z; a[15]=v.w;
  float s2 = 0.f, smu = 0.f, sls = 0.f;
  #pragma unroll
  for (int k = 0; k < 16; k++){
    s2  = fmaf(a[k], wv[k],    s2);
    smu = fmaf(a[k], wv[16+k], smu);
    sls = fmaf(a[k], wv[32+k], sls);
  }
  ew3[(size_t)e*3+0] = s2; ew3[(size_t)e*3+1] = smu; ew3[(size_t)e*3+2] = sls;
}

__global__ void zero_kernel(int* __restrict__ p, int n){
  int i = blockIdx.x*256 + threadIdx.x;
  if (i < n) p[i] = 0;
}

__global__ void count_kernel(const int* __restrict__ ei, int* __restrict__ cnt){
  int e = blockIdx.x*256 + threadIdx.x;
  if (e >= NE) return;
  atomicAdd(&cnt[ei[NE + e]], 1);
}

__global__ void bsum_kernel(const int* __restrict__ cnt, int* __restrict__ bsum){
  int i = blockIdx.x*256 + threadIdx.x;
  int v = (i < NN) ? cnt[i] : 0;
  v = wave_sum_i(v);
  __shared__ int sh[4];
  if ((threadIdx.x & 63) == 0) sh[threadIdx.x >> 6] = v;
  __syncthreads();
  if (threadIdx.x == 0) bsum[blockIdx.x] = sh[0]+sh[1]+sh[2]+sh[3];
}

__global__ void bscan_kernel(int* __restrict__ bsum, int* __restrict__ rowptr){
  __shared__ int sh[512];
  int t = threadIdx.x;
  int v = (t < NB) ? bsum[t] : 0;
  sh[t] = v; __syncthreads();
  for (int o = 1; o < 512; o <<= 1){
    int add = (t >= o) ? sh[t-o] : 0;
    __syncthreads();
    sh[t] += add;
    __syncthreads();
  }
  if (t < NB) bsum[t] = sh[t] - v;
  if (t == 0) rowptr[NN] = NE;
}

__global__ void rowptr_kernel(const int* __restrict__ cnt, const int* __restrict__ bex,
                              int* __restrict__ rowptr){
  __shared__ int sh[256];
  int t = threadIdx.x;
  int i = blockIdx.x*256 + t;
  int v = (i < NN) ? cnt[i] : 0;
  sh[t] = v; __syncthreads();
  for (int o = 1; o < 256; o <<= 1){
    int add = (t >= o) ? sh[t-o] : 0;
    __syncthreads();
    sh[t] += add;
    __syncthreads();
  }
  if (i < NN) rowptr[i] = bex[blockIdx.x] + sh[t] - v;
}

__global__ void scatter_kernel(const int* __restrict__ ei, const int* __restrict__ rowptr,
                               int* __restrict__ fill, unsigned* __restrict__ csr_u,
                               int* __restrict__ earr){
  int e = blockIdx.x*256 + threadIdx.x;
  if (e >= NE) return;
  int u = ei[e];
  int v = ei[NE + e];
  int pos = atomicAdd(&fill[v], 1);
  int slot = rowptr[v] + pos;
  csr_u[slot] = (unsigned)u;
  earr[slot] = e;
}

// ---- permute edge scalars into CSR order (sequential reads in agg) ----
__global__ void permute_ew_kernel(const int* __restrict__ earr, const float* __restrict__ ew3,
                                  float* __restrict__ ewp2, float* __restrict__ ewpmu,
                                  float* __restrict__ ewpls){
  int i = blockIdx.x*256 + threadIdx.x;
  if (i >= NE) return;
  size_t e = (size_t)earr[i];
  ewp2[i]  = ew3[e*3+0];
  ewpmu[i] = ew3[e*3+1];
  ewpls[i] = ew3[e*3+2];
}

// ---- MFMA GEMM: Y[nrows x 128] = Xb[nrows x 128] @ Wt^T, bf16 in, fp32 acc ----
// Wt is [128 cols][128 k] bf16 (pre-transposed). M-tile 128, 4 waves.
template<bool OUTF32>
__global__ __launch_bounds__(256) void gemm_bf16(const unsigned short* __restrict__ Xb,
                                                 const unsigned short* __restrict__ Wt,
                                                 void* __restrict__ Y,
                                                 const float* __restrict__ bias, int nrows){
  __shared__ uint4 As[128*16];   // 32 KB, XOR-swizzled chunks
  __shared__ uint4 Bs[128*16];   // 32 KB
  int t = threadIdx.x;
  int row0 = blockIdx.x * 128;
  #pragma unroll
  for (int p = 0; p < 8; p++){
    int idx = p*256 + t;
    int r = idx >> 4, cir = idx & 15;
    uint4 v = make_uint4(0,0,0,0);
    if (row0 + r < nrows) v = *(const uint4*)(Xb + ((size_t)(row0+r))*128 + cir*8);
    As[r*16 + (cir ^ (r & 7))] = v;
  }
  #pragma unroll
  for (int p = 0; p < 8; p++){
    int idx = p*256 + t;
    int r = idx >> 4, cir = idx & 15;
    Bs[r*16 + (cir ^ (r & 7))] = *(const uint4*)(Wt + (size_t)r*128 + cir*8);
  }
  __syncthreads();
  int w = t >> 6, l = t & 63;
  int lr = l & 15;     // A-row / B-col / D-col within tile
  int lk = l >> 4;     // k-chunk selector (0..3)
  const bf16x8* As8 = (const bf16x8*)As;
  const bf16x8* Bs8 = (const bf16x8*)Bs;
  f32x4 acc[2][8];
  f32x4 zero = {0.f, 0.f, 0.f, 0.f};
  #pragma unroll
  for (int m = 0; m < 2; m++)
    #pragma unroll
    for (int n = 0; n < 8; n++) acc[m][n] = zero;
  #pragma unroll
  for (int ks = 0; ks < 4; ks++){
    bf16x8 a0, a1, bf[8];
    { int r = w*32 + lr;      a0 = As8[r*16 + ((ks*4+lk) ^ (r&7))]; }
    { int r = w*32 + 16 + lr; a1 = As8[r*16 + ((ks*4+lk) ^ (r&7))]; }
    #pragma unroll
    for (int nt = 0; nt < 8; nt++){
      int r = nt*16 + lr;
      bf[nt] = Bs8[r*16 + ((ks*4+lk) ^ (r&7))];
    }
    #pragma unroll
    for (int nt = 0; nt < 8; nt++){
      acc[0][nt] = __builtin_amdgcn_mfma_f32_16x16x32_bf16(a0, bf[nt], acc[0][nt], 0, 0, 0);
      acc[1][nt] = __builtin_amdgcn_mfma_f32_16x16x32_bf16(a1, bf[nt], acc[1][nt], 0, 0, 0);
    }
  }
  // D layout: col = lane&15, row = (lane>>4)*4 + reg
  #pragma unroll
  for (int mt = 0; mt < 2; mt++){
    int gr0 = row0 + w*32 + mt*16 + lk*4;
    #pragma unroll
    for (int nt = 0; nt < 8; nt++){
      int col = nt*16 + lr;
      float bv = OUTF32 ? bias[col] : 0.f;
      #pragma unroll
      for (int i = 0; i < 4; i++){
        int r = gr0 + i;
        if (r < nrows){
          float o = acc[mt][nt][i];
          if constexpr (OUTF32) ((float*)Y)[(size_t)r*128 + col] = o + bv;
          else ((unsigned short*)Y)[(size_t)r*128 + col] = f2bf(o);
        }
      }
    }
  }
}

// ---- per-node dots on bf16 H (C=128): s = H.asrc, d = H.adst ----
__global__ __launch_bounds__(256) void dots_kernel(const unsigned short* __restrict__ Hb,
                                                   const float* __restrict__ asrc,
                                                   const float* __restrict__ adst,
                                                   float* __restrict__ s, float* __restrict__ d){
  int n = (blockIdx.x * blockDim.x + threadIdx.x) >> 6;
  int lane = threadIdx.x & 63;
  if (n >= NN) return;
  ushort2 q = *(const ushort2*)(Hb + (size_t)n*128 + lane*2);
  float h0 = bf2f(q.x), h1 = bf2f(q.y);
  float ps = h0*asrc[lane*2] + h1*asrc[lane*2+1];
  float pd = h0*adst[lane*2] + h1*adst[lane*2+1];
  ps = wave_sum(ps); pd = wave_sum(pd);
  if (lane == 0){ s[n] = ps; d[n] = pd; }
}

// ---- fused mu/ls dots: Y = [Hmu | Hls], writes float2 {mu,ls} ----
__global__ __launch_bounds__(256) void dots_muls_kernel(const unsigned short* __restrict__ Yb,
                                                        const float* __restrict__ amus,
                                                        const float* __restrict__ amud,
                                                        const float* __restrict__ alss,
                                                        const float* __restrict__ alsd,
                                                        float2* __restrict__ sg,
                                                        float2* __restrict__ dg){
  int n = (blockIdx.x * blockDim.x + threadIdx.x) >> 6;
  int lane = threadIdx.x & 63;
  if (n >= NN) return;
  float hmu = bf2f(Yb[(size_t)n*128 + lane]);
  float hls = bf2f(Yb[(size_t)n*128 + 64 + lane]);
  float smu = wave_sum(hmu * amus[lane]);
  float dmu = wave_sum(hmu * amud[lane]);
  float sls = wave_sum(hls * alss[lane]);
  float dls = wave_sum(hls * alsd[lane]);
  if (lane == 0){ sg[n] = make_float2(smu, sls); dg[n] = make_float2(dmu, dls); }
}

// ---- conv aggregation: C=128, no max-subtraction (logits bounded), MLP-unrolled ----
template<bool HAS_EW>
__global__ __launch_bounds__(256) void agg_conv(const unsigned short* __restrict__ Hb,
                                                const float* __restrict__ s,
                                                const float* __restrict__ dsc,
                                                const float* __restrict__ ewp,
                                                const int* __restrict__ rowptr,
                                                const unsigned* __restrict__ csr_u,
                                                const float* __restrict__ bias,
                                                const float* __restrict__ resid,
                                                unsigned short* __restrict__ out){
  int v = (blockIdx.x * blockDim.x + threadIdx.x) >> 6;
  int lane = threadIdx.x & 63;
  if (v >= NN) return;
  int rs = rowptr[v], re = rowptr[v+1];
  int deg = re - rs;
  float d_v = dsc[v];
  float pl = 0.f, acc0 = 0.f, acc1 = 0.f, ewl = 0.f;
  for (int base = rs; base < re; base += 64){
    int i = base + lane;
    int u = 0; float w = 0.f;
    if (i < re){
      u = (int)csr_u[i];
      float e = HAS_EW ? ewp[i] : 0.f;
      if (HAS_EW) ewl += e;
      float a = s[u] + d_v + e;
      float l = a > 0.f ? a : 0.2f*a;
      w = __expf(l);
    }
    pl += w;
    int nv = re - base; if (nv > 64) nv = 64;
    int j = 0;
    for (; j + 4 <= nv; j += 4){
      int u0 = __builtin_amdgcn_readlane(u, j+0);
      int u1 = __builtin_amdgcn_readlane(u, j+1);
      int u2 = __builtin_amdgcn_readlane(u, j+2);
      int u3 = __builtin_amdgcn_readlane(u, j+3);
      float w0 = rl_f(w, j+0), w1 = rl_f(w, j+1), w2 = rl_f(w, j+2), w3 = rl_f(w, j+3);
      ushort2 q0 = *(const ushort2*)(Hb + (size_t)u0*128 + lane*2);
      ushort2 q1 = *(const ushort2*)(Hb + (size_t)u1*128 + lane*2);
      ushort2 q2 = *(const ushort2*)(Hb + (size_t)u2*128 + lane*2);
      ushort2 q3 = *(const ushort2*)(Hb + (size_t)u3*128 + lane*2);
      acc0 = fmaf(w0, bf2f(q0.x), acc0); acc1 = fmaf(w0, bf2f(q0.y), acc1);
      acc0 = fmaf(w1, bf2f(q1.x), acc0); acc1 = fmaf(w1, bf2f(q1.y), acc1);
      acc0 = fmaf(w2, bf2f(q2.x), acc0); acc1 = fmaf(w2, bf2f(q2.y), acc1);
      acc0 = fmaf(w3, bf2f(q3.x), acc0); acc1 = fmaf(w3, bf2f(q3.y), acc1);
    }
    for (; j < nv; j++){
      int uu = __builtin_amdgcn_readlane(u, j);
      float ww = rl_f(w, j);
      ushort2 q = *(const ushort2*)(Hb + (size_t)uu*128 + lane*2);
      acc0 = fmaf(ww, bf2f(q.x), acc0); acc1 = fmaf(ww, bf2f(q.y), acc1);
    }
  }
  float p = wave_sum(pl);
  float ews = HAS_EW ? wave_sum(ewl) : 0.f;
  float selfa = s[v] + d_v + (HAS_EW ? ews / (float)(deg > 1 ? deg : 1) : 0.f);
  float lself = selfa > 0.f ? selfa : 0.2f*selfa;
  float wself = __expf(lself);
  p += wself;
  {
    ushort2 q = *(const ushort2*)(Hb + (size_t)v*128 + lane*2);
    acc0 = fmaf(wself, bf2f(q.x), acc0);
    acc1 = fmaf(wself, bf2f(q.y), acc1);
  }
  float inv = 1.f / p;
  int c0 = lane*2;
  float o0 = acc0*inv + bias[c0], o1 = acc1*inv + bias[c0+1];
  o0 = fmaxf(o0, 0.f); o1 = fmaxf(o1, 0.f);   // both conv layers ReLU
  if (HAS_EW){  // conv2: + initial residual (fp32)
    o0 += resid[(size_t)v*128 + c0];
    o1 += resid[(size_t)v*128 + c0 + 1];
  }
  *(ushort2*)(out + (size_t)v*128 + c0) = make_ushort2(f2bf(o0), f2bf(o1));
}

// ---- fused mu+ls aggregation: Y = [Hmu | Hls] bf16, outputs fp32 ----
__global__ __launch_bounds__(256) void agg_muls(const unsigned short* __restrict__ Yb,
                                                const float2* __restrict__ sg,
                                                const float2* __restrict__ dg,
                                                const float* __restrict__ ewpmu,
                                                const float* __restrict__ ewpls,
                                                const int* __restrict__ rowptr,
                                                const unsigned* __restrict__ csr_u,
                                                const float* __restrict__ bmu,
                                                const float* __restrict__ bls,
                                                float* __restrict__ outmu,
                                                float* __restrict__ outls){
  int v = (blockIdx.x * blockDim.x + threadIdx.x) >> 6;
  int lane = threadIdx.x & 63;
  if (v >= NN) return;
  int rs = rowptr[v], re = rowptr[v+1];
  int deg = re - rs;
  float2 dv = dg[v];
  float pmu = 0.f, pls = 0.f, accmu = 0.f, accls = 0.f, ewlmu = 0.f, ewlls = 0.f;
  for (int base = rs; base < re; base += 64){
    int i = base + lane;
    int u = 0; float wmu = 0.f, wls = 0.f;
    if (i < re){
      u = (int)csr_u[i];
      float2 su = sg[u];
      float emu = ewpmu[i], els = ewpls[i];
      ewlmu += emu; ewlls += els;
      float amu = su.x + dv.x + emu;
      float als = su.y + dv.y + els;
      float lmu = amu > 0.f ? amu : 0.2f*amu;
      float lls = als > 0.f ? als : 0.2f*als;
      wmu = __expf(lmu); wls = __expf(lls);
    }
    pmu += wmu; pls += wls;
    int nv = re - base; if (nv > 64) nv = 64;
    int j = 0;
    for (; j + 4 <= nv; j += 4){
      int u0 = __builtin_amdgcn_readlane(u, j+0);
      int u1 = __builtin_amdgcn_readlane(u, j+1);
      int u2 = __builtin_amdgcn_readlane(u, j+2);
      int u3 = __builtin_amdgcn_readlane(u, j+3);
      float wm0 = rl_f(wmu, j+0), wm1 = rl_f(wmu, j+1), wm2 = rl_f(wmu, j+2), wm3 = rl_f(wmu, j+3);
      float wl0 = rl_f(wls, j+0), wl1 = rl_f(wls, j+1), wl2 = rl_f(wls, j+2), wl3 = rl_f(wls, j+3);
      const unsigned short* r0 = Yb + (size_t)u0*128;
      const unsigned short* r1 = Yb + (size_t)u1*128;
      const unsigned short* r2 = Yb + (size_t)u2*128;
      const unsigned short* r3 = Yb + (size_t)u3*128;
      unsigned short m0 = r0[lane], l0 = r0[64+lane];
      unsigned short m1 = r1[lane], l1 = r1[64+lane];
      unsigned short m2 = r2[lane], l2 = r2[64+lane];
      unsigned short m3 = r3[lane], l3 = r3[64+lane];
      accmu = fmaf(wm0, bf2f(m0), accmu); accls = fmaf(wl0, bf2f(l0), accls);
      accmu = fmaf(wm1, bf2f(m1), accmu); accls = fmaf(wl1, bf2f(l1), accls);
      accmu = fmaf(wm2, bf2f(m2), accmu); accls = fmaf(wl2, bf2f(l2), accls);
      accmu = fmaf(wm3, bf2f(m3), accmu); accls = fmaf(wl3, bf2f(l3), accls);
    }
    for (; j < nv; j++){
      int uu = __builtin_amdgcn_readlane(u, j);
      float wm = rl_f(wmu, j), wl = rl_f(wls, j);
      const unsigned short* rr = Yb + (size_t)uu*128;
      accmu = fmaf(wm, bf2f(rr[lane]), accmu);
      accls = fmaf(wl, bf2f(rr[64+lane]), accls);
    }
  }
  float Pmu = wave_sum(pmu), Pls = wave_sum(pls);
  float Emu = wave_sum(ewlmu), Els = wave_sum(ewlls);
  float2 sv = sg[v];
  float dnm = (float)(deg > 1 ? deg : 1);
  float selfmu = sv.x + dv.x + Emu/dnm;
  float selfls = sv.y + dv.y + Els/dnm;
  float lmu = selfmu > 0.f ? selfmu : 0.2f*selfmu;
  float lls = selfls > 0.f ? selfls : 0.2f*selfls;
  float wmu_s = __expf(lmu), wls_s = __expf(lls);
  Pmu += wmu_s; Pls += wls_s;
  {
    const unsigned short* rr = Yb + (size_t)v*128;
    accmu = fmaf(wmu_s, bf2f(rr[lane]), accmu);
    accls = fmaf(wls_s, bf2f(rr[64+lane]), accls);
  }
  outmu[(size_t)v*64 + lane] = accmu/Pmu + bmu[lane];
  outls[(size_t)v*64 + lane] = accls/Pls + bls[lane];
}

extern "C" void kernel_launch(void* const* d_in, const int* in_sizes, int n_in,
                              void* d_out, int out_size, void* d_ws, size_t ws_size,
                              hipStream_t stream){
  const float* x    = (const float*)d_in[0];
  const int*   ei   = (const int*)  d_in[1];
  const float* ea   = (const float*)d_in[2];
  const float* W1   = (const float*)d_in[3];
  const float* a1s  = (const float*)d_in[4];
  const float* a1d  = (const float*)d_in[5];
  const float* b1   = (const float*)d_in[6];
  const float* W2   = (const float*)d_in[7];
  const float* a2s  = (const float*)d_in[8];
  const float* a2d  = (const float*)d_in[9];
  const float* b2   = (const float*)d_in[10];
  const float* We2  = (const float*)d_in[11];
  const float* ae2  = (const float*)d_in[12];
  const float* Wr   = (const float*)d_in[13];
  const float* br   = (const float*)d_in[14];
  const float* Wmu  = (const float*)d_in[15];
  const float* amus = (const float*)d_in[16];
  const float* amud = (const float*)d_in[17];
  const float* bmu  = (const float*)d_in[18];
  const float* Wemu = (const float*)d_in[19];
  const float* aemu = (const float*)d_in[20];
  const float* Wls  = (const float*)d_in[21];
  const float* alss = (const float*)d_in[22];
  const float* alsd = (const float*)d_in[23];
  const float* bls  = (const float*)d_in[24];
  const float* Wels = (const float*)d_in[25];
  const float* aels = (const float*)d_in[26];

  char* base = (char*)d_ws;
  size_t off = 0;
  auto alloc = [&](size_t bytes)->char*{
    char* p = base + off;
    off = (off + bytes + 511) & ~(size_t)511;
    return p;
  };
  float*  ew3    = (float*)alloc((size_t)NE*12);      // interleaved {s2,smu,sls} by e
  float*  ewp2   = (float*)alloc((size_t)NE*4);       // CSR-ordered
  float*  ewpmu  = (float*)alloc((size_t)NE*4);
  float*  ewpls  = (float*)alloc((size_t)NE*4);
  int*    rowptr = (int*)  alloc((size_t)(NN+1)*4);
  int*    cnt    = (int*)  alloc((size_t)2*NN*4);
  int*    fill   = cnt + NN;
  int*    bsum   = (int*)  alloc(512*4);
  unsigned* csr_u= (unsigned*)alloc((size_t)NE*4);
  int*    earr   = (int*)  alloc((size_t)NE*4);
  float*  wv     = (float*)alloc(48*4);
  float*  s1     = (float*)alloc((size_t)NN*4);
  float*  d1     = (float*)alloc((size_t)NN*4);
  float2* sg2    = (float2*)alloc((size_t)NN*8);
  float2* dg2    = (float2*)alloc((size_t)NN*8);
  unsigned short* W1t  = (unsigned short*)alloc(128*128*2);
  unsigned short* W2t  = (unsigned short*)alloc(128*128*2);
  unsigned short* Wrt  = (unsigned short*)alloc(128*128*2);
  unsigned short* Wmlt = (unsigned short*)alloc(128*128*2);
  unsigned short* Xb   = (unsigned short*)alloc((size_t)NN*128*2);
  unsigned short* bufA = (unsigned short*)alloc((size_t)NN*128*2);  // H1 -> H2 -> Y(muls)
  unsigned short* bufB = (unsigned short*)alloc((size_t)NN*128*2);  // h1 -> h
  if (off > ws_size) return;

  float* outF = (float*)d_out;   // XR (fp32 [NN][128]) then [mu | logstd]
  float* muO  = outF;
  float* lsO  = outF + (size_t)NN*64;

  const int EB  = (NE + 255)/256;
  const int WB  = (NN*64 + 255)/256;
  const int GB  = (NN + 127)/128;      // 782 MFMA blocks
  const int CB  = (NN*128/8 + 255)/256;

  // precompute + graph build
  prep_w_kernel<<<4, 256, 0, stream>>>(W1, W2, Wr, Wmu, Wls, W1t, W2t, Wrt, Wmlt);
  wvec_kernel<<<1, 64, 0, stream>>>(We2, ae2, Wemu, aemu, Wels, aels, wv);
  cast_x_kernel<<<CB, 256, 0, stream>>>(x, Xb);
  edge_scalar_kernel<<<EB, 256, 0, stream>>>(ea, wv, ew3);
  zero_kernel<<<(2*NN + 255)/256, 256, 0, stream>>>(cnt, 2*NN);
  count_kernel<<<EB, 256, 0, stream>>>(ei, cnt);
  bsum_kernel<<<NB, 256, 0, stream>>>(cnt, bsum);
  bscan_kernel<<<1, 512, 0, stream>>>(bsum, rowptr);
  rowptr_kernel<<<NB, 256, 0, stream>>>(cnt, bsum, rowptr);
  scatter_kernel<<<EB, 256, 0, stream>>>(ei, rowptr, fill, csr_u, earr);
  permute_ew_kernel<<<EB, 256, 0, stream>>>(earr, ew3, ewp2, ewpmu, ewpls);

  // conv1
  gemm_bf16<false><<<GB, 256, 0, stream>>>(Xb, W1t, bufA, nullptr, NN);           // H1
  dots_kernel<<<WB, 256, 0, stream>>>(bufA, a1s, a1d, s1, d1);
  agg_conv<false><<<WB, 256, 0, stream>>>(bufA, s1, d1, nullptr, rowptr, csr_u,
                                          b1, nullptr, bufB);                     // h1
  // conv2 + residual
  gemm_bf16<false><<<GB, 256, 0, stream>>>(bufB, W2t, bufA, nullptr, NN);         // H2
  dots_kernel<<<WB, 256, 0, stream>>>(bufA, a2s, a2d, s1, d1);
  gemm_bf16<true><<<GB, 256, 0, stream>>>(Xb, Wrt, outF, br, NN);                 // XR -> d_out
  agg_conv<true><<<WB, 256, 0, stream>>>(bufA, s1, d1, ewp2, rowptr, csr_u,
                                         b2, outF, bufB);                         // h
  // mu + logstd (fused)
  gemm_bf16<false><<<GB, 256, 0, stream>>>(bufB, Wmlt, bufA, nullptr, NN);        // [Hmu|Hls]
  dots_muls_kernel<<<WB, 256, 0, stream>>>(bufA, amus, amud, alss, alsd, sg2, dg2);
  agg_muls<<<WB, 256, 0, stream>>>(bufA, sg2, dg2, ewpmu, ewpls, rowptr, csr_u,
                                   bmu, bls, muO, lsO);
}

// Round 4
// 623.951 us; speedup vs baseline: 2.1083x; 1.0036x over previous
//
#include <hip/hip_runtime.h>

#define NN 100000
#define NE 1600000
#define NB ((NN + 255) / 256)   // 391

typedef __attribute__((ext_vector_type(8))) short bf16x8;
typedef __attribute__((ext_vector_type(4))) float f32x4;

__device__ __forceinline__ float wave_sum(float v){
  #pragma unroll
  for (int o = 32; o; o >>= 1) v += __shfl_xor(v, o, 64);
  return v;
}
__device__ __forceinline__ int wave_sum_i(int v){
  #pragma unroll
  for (int o = 32; o; o >>= 1) v += __shfl_xor(v, o, 64);
  return v;
}
__device__ __forceinline__ float bf2f(unsigned short x){
  return __uint_as_float(((unsigned)x) << 16);
}
__device__ __forceinline__ unsigned short f2bf(float f){
  unsigned u = __float_as_uint(f);
  return (unsigned short)((u + 0x7FFFu + ((u >> 16) & 1u)) >> 16);
}
__device__ __forceinline__ float rl_f(float v, int j){
  return __uint_as_float(__builtin_amdgcn_readlane(__float_as_uint(v), j));
}

// ---- weight prep: transpose + bf16 cast. block3 = [Wmu | Wls] concat ----
__global__ void prep_w_kernel(const float* __restrict__ W1, const float* __restrict__ W2,
                              const float* __restrict__ Wr, const float* __restrict__ Wmu,
                              const float* __restrict__ Wls,
                              unsigned short* __restrict__ W1t, unsigned short* __restrict__ W2t,
                              unsigned short* __restrict__ Wrt, unsigned short* __restrict__ Wmlt){
  int b = blockIdx.x, t = threadIdx.x;
  for (int it = 0; it < 64; it++){
    int idx = it*256 + t;          // 16384 entries
    int k = idx >> 7, c = idx & 127;
    float v; unsigned short* dst;
    if (b == 0){ v = W1[k*128+c]; dst = W1t; }
    else if (b == 1){ v = W2[k*128+c]; dst = W2t; }
    else if (b == 2){ v = Wr[k*128+c]; dst = Wrt; }
    else { v = (c < 64) ? Wmu[k*64+c] : Wls[k*64+(c-64)]; dst = Wmlt; }
    dst[c*128 + k] = f2bf(v);      // [col][k]
  }
}

__global__ void wvec_kernel(const float* __restrict__ We2, const float* __restrict__ ae2,
                            const float* __restrict__ Wemu, const float* __restrict__ aemu,
                            const float* __restrict__ Wels, const float* __restrict__ aels,
                            float* __restrict__ wv){
  int t = threadIdx.x;
  if (t < 16){
    float s = 0.f; for (int c = 0; c < 128; c++) s += We2[t*128+c]*ae2[c];
    wv[t] = s;
  } else if (t < 32){
    int k = t-16; float s = 0.f; for (int c = 0; c < 64; c++) s += Wemu[k*64+c]*aemu[c];
    wv[16+k] = s;
  } else if (t < 48){
    int k = t-32; float s = 0.f; for (int c = 0; c < 64; c++) s += Wels[k*64+c]*aels[c];
    wv[32+k] = s;
  }
}

__global__ void cast_x_kernel(const float* __restrict__ x, unsigned short* __restrict__ Xb){
  int i = blockIdx.x*256 + threadIdx.x;   // 8 elems each
  if (i >= NN*128/8) return;
  const float4* src = (const float4*)x + (size_t)i*2;
  float4 v0 = src[0], v1 = src[1];
  ushort4 o0 = make_ushort4(f2bf(v0.x), f2bf(v0.y), f2bf(v0.z), f2bf(v0.w));
  ushort4 o1 = make_ushort4(f2bf(v1.x), f2bf(v1.y), f2bf(v1.z), f2bf(v1.w));
  *(ushort4*)(Xb + (size_t)i*8)     = o0;
  *(ushort4*)(Xb + (size_t)i*8 + 4) = o1;
}

// ---- per-edge attention scalars: ew2[e] (conv2), ewmuls[e] = {mu, ls} ----
__global__ void edge_scalar_kernel(const float* __restrict__ ea, const float* __restrict__ wv,
                                   float* __restrict__ ew2, float2* __restrict__ ewmuls){
  int e = blockIdx.x*256 + threadIdx.x;
  if (e >= NE) return;
  const float4* p = (const float4*)(ea + (size_t)e*16);
  float a[16]; float4 v;
  v = p[0]; a[0]=v.x; a[1]=v.y; a[2]=v.z; a[3]=v.w;
  v = p[1]; a[4]=v.x; a[5]=v.y; a[6]=v.z; a[7]=v.w;
  v = p[2]; a[8]=v.x; a[9]=v.y; a[10]=v.z; a[11]=v.w;
  v = p[3]; a[12]=v.x; a[13]=v.y; a[14]=v.z; a[15]=v.w;
  float s2 = 0.f, smu = 0.f, sls = 0.f;
  #pragma unroll
  for (int k = 0; k < 16; k++){
    s2  = fmaf(a[k], wv[k],    s2);
    smu = fmaf(a[k], wv[16+k], smu);
    sls = fmaf(a[k], wv[32+k], sls);
  }
  ew2[e] = s2;
  ewmuls[e] = make_float2(smu, sls);
}

__global__ void zero_kernel(int* __restrict__ p, int n){
  int i = blockIdx.x*256 + threadIdx.x;
  if (i < n) p[i] = 0;
}

__global__ void count_kernel(const int* __restrict__ ei, int* __restrict__ cnt){
  int e = blockIdx.x*256 + threadIdx.x;
  if (e >= NE) return;
  atomicAdd(&cnt[ei[NE + e]], 1);
}

__global__ void bsum_kernel(const int* __restrict__ cnt, int* __restrict__ bsum){
  int i = blockIdx.x*256 + threadIdx.x;
  int v = (i < NN) ? cnt[i] : 0;
  v = wave_sum_i(v);
  __shared__ int sh[4];
  if ((threadIdx.x & 63) == 0) sh[threadIdx.x >> 6] = v;
  __syncthreads();
  if (threadIdx.x == 0) bsum[blockIdx.x] = sh[0]+sh[1]+sh[2]+sh[3];
}

__global__ void bscan_kernel(int* __restrict__ bsum, int* __restrict__ rowptr){
  __shared__ int sh[512];
  int t = threadIdx.x;
  int v = (t < NB) ? bsum[t] : 0;
  sh[t] = v; __syncthreads();
  for (int o = 1; o < 512; o <<= 1){
    int add = (t >= o) ? sh[t-o] : 0;
    __syncthreads();
    sh[t] += add;
    __syncthreads();
  }
  if (t < NB) bsum[t] = sh[t] - v;
  if (t == 0) rowptr[NN] = NE;
}

__global__ void rowptr_kernel(const int* __restrict__ cnt, const int* __restrict__ bex,
                              int* __restrict__ rowptr){
  __shared__ int sh[256];
  int t = threadIdx.x;
  int i = blockIdx.x*256 + t;
  int v = (i < NN) ? cnt[i] : 0;
  sh[t] = v; __syncthreads();
  for (int o = 1; o < 256; o <<= 1){
    int add = (t >= o) ? sh[t-o] : 0;
    __syncthreads();
    sh[t] += add;
    __syncthreads();
  }
  if (i < NN) rowptr[i] = bex[blockIdx.x] + sh[t] - v;
}

// ---- single random 8B write per edge: csr8[slot] = {u, e} ----
__global__ void scatter_kernel(const int* __restrict__ ei, const int* __restrict__ rowptr,
                               int* __restrict__ fill, uint2* __restrict__ csr8){
  int e = blockIdx.x*256 + threadIdx.x;
  if (e >= NE) return;
  int u = ei[e];
  int v = ei[NE + e];
  int pos = atomicAdd(&fill[v], 1);
  csr8[rowptr[v] + pos] = make_uint2((unsigned)u, (unsigned)e);
}

// ---- MFMA GEMM: Y[nrows x 128] = Xb[nrows x 128] @ Wt^T, bf16 in, fp32 acc ----
template<bool OUTF32>
__global__ __launch_bounds__(256) void gemm_bf16(const unsigned short* __restrict__ Xb,
                                                 const unsigned short* __restrict__ Wt,
                                                 void* __restrict__ Y,
                                                 const float* __restrict__ bias, int nrows){
  __shared__ uint4 As[128*16];   // 32 KB, XOR-swizzled chunks
  __shared__ uint4 Bs[128*16];   // 32 KB
  int t = threadIdx.x;
  int row0 = blockIdx.x * 128;
  #pragma unroll
  for (int p = 0; p < 8; p++){
    int idx = p*256 + t;
    int r = idx >> 4, cir = idx & 15;
    uint4 v = make_uint4(0,0,0,0);
    if (row0 + r < nrows) v = *(const uint4*)(Xb + ((size_t)(row0+r))*128 + cir*8);
    As[r*16 + (cir ^ (r & 7))] = v;
  }
  #pragma unroll
  for (int p = 0; p < 8; p++){
    int idx = p*256 + t;
    int r = idx >> 4, cir = idx & 15;
    Bs[r*16 + (cir ^ (r & 7))] = *(const uint4*)(Wt + (size_t)r*128 + cir*8);
  }
  __syncthreads();
  int w = t >> 6, l = t & 63;
  int lr = l & 15;
  int lk = l >> 4;
  const bf16x8* As8 = (const bf16x8*)As;
  const bf16x8* Bs8 = (const bf16x8*)Bs;
  f32x4 acc[2][8];
  f32x4 zero = {0.f, 0.f, 0.f, 0.f};
  #pragma unroll
  for (int m = 0; m < 2; m++)
    #pragma unroll
    for (int n = 0; n < 8; n++) acc[m][n] = zero;
  #pragma unroll
  for (int ks = 0; ks < 4; ks++){
    bf16x8 a0, a1, bf[8];
    { int r = w*32 + lr;      a0 = As8[r*16 + ((ks*4+lk) ^ (r&7))]; }
    { int r = w*32 + 16 + lr; a1 = As8[r*16 + ((ks*4+lk) ^ (r&7))]; }
    #pragma unroll
    for (int nt = 0; nt < 8; nt++){
      int r = nt*16 + lr;
      bf[nt] = Bs8[r*16 + ((ks*4+lk) ^ (r&7))];
    }
    #pragma unroll
    for (int nt = 0; nt < 8; nt++){
      acc[0][nt] = __builtin_amdgcn_mfma_f32_16x16x32_bf16(a0, bf[nt], acc[0][nt], 0, 0, 0);
      acc[1][nt] = __builtin_amdgcn_mfma_f32_16x16x32_bf16(a1, bf[nt], acc[1][nt], 0, 0, 0);
    }
  }
  #pragma unroll
  for (int mt = 0; mt < 2; mt++){
    int gr0 = row0 + w*32 + mt*16 + lk*4;
    #pragma unroll
    for (int nt = 0; nt < 8; nt++){
      int col = nt*16 + lr;
      float bv = OUTF32 ? bias[col] : 0.f;
      #pragma unroll
      for (int i = 0; i < 4; i++){
        int r = gr0 + i;
        if (r < nrows){
          float o = acc[mt][nt][i];
          if constexpr (OUTF32) ((float*)Y)[(size_t)r*128 + col] = o + bv;
          else ((unsigned short*)Y)[(size_t)r*128 + col] = f2bf(o);
        }
      }
    }
  }
}

// ---- per-node dots on bf16 H (C=128) ----
__global__ __launch_bounds__(256) void dots_kernel(const unsigned short* __restrict__ Hb,
                                                   const float* __restrict__ asrc,
                                                   const float* __restrict__ adst,
                                                   float* __restrict__ s, float* __restrict__ d){
  int n = (blockIdx.x * blockDim.x + threadIdx.x) >> 6;
  int lane = threadIdx.x & 63;
  if (n >= NN) return;
  ushort2 q = *(const ushort2*)(Hb + (size_t)n*128 + lane*2);
  float h0 = bf2f(q.x), h1 = bf2f(q.y);
  float ps = h0*asrc[lane*2] + h1*asrc[lane*2+1];
  float pd = h0*adst[lane*2] + h1*adst[lane*2+1];
  ps = wave_sum(ps); pd = wave_sum(pd);
  if (lane == 0){ s[n] = ps; d[n] = pd; }
}

// ---- fused mu/ls dots ----
__global__ __launch_bounds__(256) void dots_muls_kernel(const unsigned short* __restrict__ Yb,
                                                        const float* __restrict__ amus,
                                                        const float* __restrict__ amud,
                                                        const float* __restrict__ alss,
                                                        const float* __restrict__ alsd,
                                                        float2* __restrict__ sg,
                                                        float2* __restrict__ dg){
  int n = (blockIdx.x * blockDim.x + threadIdx.x) >> 6;
  int lane = threadIdx.x & 63;
  if (n >= NN) return;
  float hmu = bf2f(Yb[(size_t)n*128 + lane]);
  float hls = bf2f(Yb[(size_t)n*128 + 64 + lane]);
  float smu = wave_sum(hmu * amus[lane]);
  float dmu = wave_sum(hmu * amud[lane]);
  float sls = wave_sum(hls * alss[lane]);
  float dls = wave_sum(hls * alsd[lane]);
  if (lane == 0){ sg[n] = make_float2(smu, sls); dg[n] = make_float2(dmu, dls); }
}

// ---- conv aggregation: C=128, MLP-unrolled x8, random ew2[e] reads (L3-hit) ----
template<bool HAS_EW>
__global__ __launch_bounds__(256) void agg_conv(const unsigned short* __restrict__ Hb,
                                                const float* __restrict__ s,
                                                const float* __restrict__ dsc,
                                                const float* __restrict__ ew2,
                                                const int* __restrict__ rowptr,
                                                const uint2* __restrict__ csr8,
                                                const float* __restrict__ bias,
                                                const float* __restrict__ resid,
                                                unsigned short* __restrict__ out){
  int v = (blockIdx.x * blockDim.x + threadIdx.x) >> 6;
  int lane = threadIdx.x & 63;
  if (v >= NN) return;
  int rs = rowptr[v], re = rowptr[v+1];
  int deg = re - rs;
  float d_v = dsc[v];
  float pl = 0.f, acc0 = 0.f, acc1 = 0.f, ewl = 0.f;
  for (int base = rs; base < re; base += 64){
    int i = base + lane;
    int u = 0; float w = 0.f;
    if (i < re){
      uint2 rec = csr8[i];
      u = (int)rec.x;
      float e = HAS_EW ? ew2[rec.y] : 0.f;
      if (HAS_EW) ewl += e;
      float a = s[u] + d_v + e;
      float l = a > 0.f ? a : 0.2f*a;
      w = __expf(l);
    }
    pl += w;
    int nv = re - base; if (nv > 64) nv = 64;
    int j = 0;
    for (; j + 8 <= nv; j += 8){
      ushort2 q[8];
      float wj[8];
      #pragma unroll
      for (int k = 0; k < 8; k++){
        int uk = __builtin_amdgcn_readlane(u, j+k);
        wj[k] = rl_f(w, j+k);
        q[k] = *(const ushort2*)(Hb + (size_t)uk*128 + lane*2);
      }
      #pragma unroll
      for (int k = 0; k < 8; k++){
        acc0 = fmaf(wj[k], bf2f(q[k].x), acc0);
        acc1 = fmaf(wj[k], bf2f(q[k].y), acc1);
      }
    }
    for (; j < nv; j++){
      int uu = __builtin_amdgcn_readlane(u, j);
      float ww = rl_f(w, j);
      ushort2 q = *(const ushort2*)(Hb + (size_t)uu*128 + lane*2);
      acc0 = fmaf(ww, bf2f(q.x), acc0); acc1 = fmaf(ww, bf2f(q.y), acc1);
    }
  }
  float p = wave_sum(pl);
  float ews = HAS_EW ? wave_sum(ewl) : 0.f;
  float selfa = s[v] + d_v + (HAS_EW ? ews / (float)(deg > 1 ? deg : 1) : 0.f);
  float lself = selfa > 0.f ? selfa : 0.2f*selfa;
  float wself = __expf(lself);
  p += wself;
  {
    ushort2 q = *(const ushort2*)(Hb + (size_t)v*128 + lane*2);
    acc0 = fmaf(wself, bf2f(q.x), acc0);
    acc1 = fmaf(wself, bf2f(q.y), acc1);
  }
  float inv = 1.f / p;
  int c0 = lane*2;
  float o0 = acc0*inv + bias[c0], o1 = acc1*inv + bias[c0+1];
  o0 = fmaxf(o0, 0.f); o1 = fmaxf(o1, 0.f);
  if (HAS_EW){
    o0 += resid[(size_t)v*128 + c0];
    o1 += resid[(size_t)v*128 + c0 + 1];
  }
  *(ushort2*)(out + (size_t)v*128 + c0) = make_ushort2(f2bf(o0), f2bf(o1));
}

// ---- fused mu+ls aggregation: random ewmuls[e] float2 reads (L3-hit) ----
__global__ __launch_bounds__(256) void agg_muls(const unsigned short* __restrict__ Yb,
                                                const float2* __restrict__ sg,
                                                const float2* __restrict__ dg,
                                                const float2* __restrict__ ewmuls,
                                                const int* __restrict__ rowptr,
                                                const uint2* __restrict__ csr8,
                                                const float* __restrict__ bmu,
                                                const float* __restrict__ bls,
                                                float* __restrict__ outmu,
                                                float* __restrict__ outls){
  int v = (blockIdx.x * blockDim.x + threadIdx.x) >> 6;
  int lane = threadIdx.x & 63;
  if (v >= NN) return;
  int rs = rowptr[v], re = rowptr[v+1];
  int deg = re - rs;
  float2 dv = dg[v];
  float pmu = 0.f, pls = 0.f, accmu = 0.f, accls = 0.f, ewlmu = 0.f, ewlls = 0.f;
  for (int base = rs; base < re; base += 64){
    int i = base + lane;
    int u = 0; float wmu = 0.f, wls = 0.f;
    if (i < re){
      uint2 rec = csr8[i];
      u = (int)rec.x;
      float2 su = sg[u];
      float2 ee = ewmuls[rec.y];
      ewlmu += ee.x; ewlls += ee.y;
      float amu = su.x + dv.x + ee.x;
      float als = su.y + dv.y + ee.y;
      float lmu = amu > 0.f ? amu : 0.2f*amu;
      float lls = als > 0.f ? als : 0.2f*als;
      wmu = __expf(lmu); wls = __expf(lls);
    }
    pmu += wmu; pls += wls;
    int nv = re - base; if (nv > 64) nv = 64;
    int j = 0;
    for (; j + 4 <= nv; j += 4){
      int u0 = __builtin_amdgcn_readlane(u, j+0);
      int u1 = __builtin_amdgcn_readlane(u, j+1);
      int u2 = __builtin_amdgcn_readlane(u, j+2);
      int u3 = __builtin_amdgcn_readlane(u, j+3);
      float wm0 = rl_f(wmu, j+0), wm1 = rl_f(wmu, j+1), wm2 = rl_f(wmu, j+2), wm3 = rl_f(wmu, j+3);
      float wl0 = rl_f(wls, j+0), wl1 = rl_f(wls, j+1), wl2 = rl_f(wls, j+2), wl3 = rl_f(wls, j+3);
      const unsigned short* r0 = Yb + (size_t)u0*128;
      const unsigned short* r1 = Yb + (size_t)u1*128;
      const unsigned short* r2 = Yb + (size_t)u2*128;
      const unsigned short* r3 = Yb + (size_t)u3*128;
      unsigned short m0 = r0[lane], l0 = r0[64+lane];
      unsigned short m1 = r1[lane], l1 = r1[64+lane];
      unsigned short m2 = r2[lane], l2 = r2[64+lane];
      unsigned short m3 = r3[lane], l3 = r3[64+lane];
      accmu = fmaf(wm0, bf2f(m0), accmu); accls = fmaf(wl0, bf2f(l0), accls);
      accmu = fmaf(wm1, bf2f(m1), accmu); accls = fmaf(wl1, bf2f(l1), accls);
      accmu = fmaf(wm2, bf2f(m2), accmu); accls = fmaf(wl2, bf2f(l2), accls);
      accmu = fmaf(wm3, bf2f(m3), accmu); accls = fmaf(wl3, bf2f(l3), accls);
    }
    for (; j < nv; j++){
      int uu = __builtin_amdgcn_readlane(u, j);
      float wm = rl_f(wmu, j), wl = rl_f(wls, j);
      const unsigned short* rr = Yb + (size_t)uu*128;
      accmu = fmaf(wm, bf2f(rr[lane]), accmu);
      accls = fmaf(wl, bf2f(rr[64+lane]), accls);
    }
  }
  float Pmu = wave_sum(pmu), Pls = wave_sum(pls);
  float Emu = wave_sum(ewlmu), Els = wave_sum(ewlls);
  float2 sv = sg[v];
  float dnm = (float)(deg > 1 ? deg : 1);
  float selfmu = sv.x + dv.x + Emu/dnm;
  float selfls = sv.y + dv.y + Els/dnm;
  float lmu = selfmu > 0.f ? selfmu : 0.2f*selfmu;
  float lls = selfls > 0.f ? selfls : 0.2f*selfls;
  float wmu_s = __expf(lmu), wls_s = __expf(lls);
  Pmu += wmu_s; Pls += wls_s;
  {
    const unsigned short* rr = Yb + (size_t)v*128;
    accmu = fmaf(wmu_s, bf2f(rr[lane]), accmu);
    accls = fmaf(wls_s, bf2f(rr[64+lane]), accls);
  }
  outmu[(size_t)v*64 + lane] = accmu/Pmu + bmu[lane];
  outls[(size_t)v*64 + lane] = accls/Pls + bls[lane];
}

extern "C" void kernel_launch(void* const* d_in, const int* in_sizes, int n_in,
                              void* d_out, int out_size, void* d_ws, size_t ws_size,
                              hipStream_t stream){
  const float* x    = (const float*)d_in[0];
  const int*   ei   = (const int*)  d_in[1];
  const float* ea   = (const float*)d_in[2];
  const float* W1   = (const float*)d_in[3];
  const float* a1s  = (const float*)d_in[4];
  const float* a1d  = (const float*)d_in[5];
  const float* b1   = (const float*)d_in[6];
  const float* W2   = (const float*)d_in[7];
  const float* a2s  = (const float*)d_in[8];
  const float* a2d  = (const float*)d_in[9];
  const float* b2   = (const float*)d_in[10];
  const float* We2  = (const float*)d_in[11];
  const float* ae2  = (const float*)d_in[12];
  const float* Wr   = (const float*)d_in[13];
  const float* br   = (const float*)d_in[14];
  const float* Wmu  = (const float*)d_in[15];
  const float* amus = (const float*)d_in[16];
  const float* amud = (const float*)d_in[17];
  const float* bmu  = (const float*)d_in[18];
  const float* Wemu = (const float*)d_in[19];
  const float* aemu = (const float*)d_in[20];
  const float* Wls  = (const float*)d_in[21];
  const float* alss = (const float*)d_in[22];
  const float* alsd = (const float*)d_in[23];
  const float* bls  = (const float*)d_in[24];
  const float* Wels = (const float*)d_in[25];
  const float* aels = (const float*)d_in[26];

  char* base = (char*)d_ws;
  size_t off = 0;
  auto alloc = [&](size_t bytes)->char*{
    char* p = base + off;
    off = (off + bytes + 511) & ~(size_t)511;
    return p;
  };
  float*  ew2    = (float*)alloc((size_t)NE*4);
  float2* ewmuls = (float2*)alloc((size_t)NE*8);
  int*    rowptr = (int*)  alloc((size_t)(NN+1)*4);
  int*    cnt    = (int*)  alloc((size_t)2*NN*4);
  int*    fill   = cnt + NN;
  int*    bsum   = (int*)  alloc(512*4);
  uint2*  csr8   = (uint2*)alloc((size_t)NE*8);
  float*  wv     = (float*)alloc(48*4);
  float*  s1     = (float*)alloc((size_t)NN*4);
  float*  d1     = (float*)alloc((size_t)NN*4);
  float2* sg2    = (float2*)alloc((size_t)NN*8);
  float2* dg2    = (float2*)alloc((size_t)NN*8);
  unsigned short* W1t  = (unsigned short*)alloc(128*128*2);
  unsigned short* W2t  = (unsigned short*)alloc(128*128*2);
  unsigned short* Wrt  = (unsigned short*)alloc(128*128*2);
  unsigned short* Wmlt = (unsigned short*)alloc(128*128*2);
  unsigned short* Xb   = (unsigned short*)alloc((size_t)NN*128*2);
  unsigned short* bufA = (unsigned short*)alloc((size_t)NN*128*2);  // H1 -> H2 -> Y(muls)
  unsigned short* bufB = (unsigned short*)alloc((size_t)NN*128*2);  // h1 -> h
  if (off > ws_size) return;

  float* outF = (float*)d_out;   // XR (fp32 [NN][128]) then [mu | logstd]
  float* muO  = outF;
  float* lsO  = outF + (size_t)NN*64;

  const int EB  = (NE + 255)/256;
  const int WB  = (NN*64 + 255)/256;
  const int GB  = (NN + 127)/128;
  const int CB  = (NN*128/8 + 255)/256;

  // precompute + graph build
  prep_w_kernel<<<4, 256, 0, stream>>>(W1, W2, Wr, Wmu, Wls, W1t, W2t, Wrt, Wmlt);
  wvec_kernel<<<1, 64, 0, stream>>>(We2, ae2, Wemu, aemu, Wels, aels, wv);
  cast_x_kernel<<<CB, 256, 0, stream>>>(x, Xb);
  edge_scalar_kernel<<<EB, 256, 0, stream>>>(ea, wv, ew2, ewmuls);
  zero_kernel<<<(2*NN + 255)/256, 256, 0, stream>>>(cnt, 2*NN);
  count_kernel<<<EB, 256, 0, stream>>>(ei, cnt);
  bsum_kernel<<<NB, 256, 0, stream>>>(cnt, bsum);
  bscan_kernel<<<1, 512, 0, stream>>>(bsum, rowptr);
  rowptr_kernel<<<NB, 256, 0, stream>>>(cnt, bsum, rowptr);
  scatter_kernel<<<EB, 256, 0, stream>>>(ei, rowptr, fill, csr8);

  // conv1
  gemm_bf16<false><<<GB, 256, 0, stream>>>(Xb, W1t, bufA, nullptr, NN);           // H1
  dots_kernel<<<WB, 256, 0, stream>>>(bufA, a1s, a1d, s1, d1);
  agg_conv<false><<<WB, 256, 0, stream>>>(bufA, s1, d1, nullptr, rowptr, csr8,
                                          b1, nullptr, bufB);                     // h1
  // conv2 + residual
  gemm_bf16<false><<<GB, 256, 0, stream>>>(bufB, W2t, bufA, nullptr, NN);         // H2
  dots_kernel<<<WB, 256, 0, stream>>>(bufA, a2s, a2d, s1, d1);
  gemm_bf16<true><<<GB, 256, 0, stream>>>(Xb, Wrt, outF, br, NN);                 // XR -> d_out
  agg_conv<true><<<WB, 256, 0, stream>>>(bufA, s1, d1, ew2, rowptr, csr8,
                                         b2, outF, bufB);                         // h
  // mu + logstd (fused)
  gemm_bf16<false><<<GB, 256, 0, stream>>>(bufB, Wmlt, bufA, nullptr, NN);        // [Hmu|Hls]
  dots_muls_kernel<<<WB, 256, 0, stream>>>(bufA, amus, amud, alss, alsd, sg2, dg2);
  agg_muls<<<WB, 256, 0, stream>>>(bufA, sg2, dg2, ewmuls, rowptr, csr8,
                                   bmu, bls, muO, lsO);
}

// Round 5
// 515.771 us; speedup vs baseline: 2.5505x; 1.2097x over previous
//
#include <hip/hip_runtime.h>

#define NN 100000
#define NE 1600000
#define BSH 9
#define NBUK 196          // ceil(NN / 512)

typedef __attribute__((ext_vector_type(8))) short bf16x8;
typedef __attribute__((ext_vector_type(4))) float f32x4;

__device__ __forceinline__ float wave_sum(float v){
  #pragma unroll
  for (int o = 32; o; o >>= 1) v += __shfl_xor(v, o, 64);
  return v;
}
__device__ __forceinline__ float bf2f(unsigned short x){
  return __uint_as_float(((unsigned)x) << 16);
}
__device__ __forceinline__ unsigned short f2bf(float f){
  unsigned u = __float_as_uint(f);
  return (unsigned short)((u + 0x7FFFu + ((u >> 16) & 1u)) >> 16);
}
__device__ __forceinline__ float rl_f(float v, int j){
  return __uint_as_float(__builtin_amdgcn_readlane(__float_as_uint(v), j));
}

// ---- weight prep: transpose + bf16. Wmlt interleaved: col 2c=Wmu[:,c], 2c+1=Wls[:,c] ----
__global__ void prep_w_kernel(const float* __restrict__ W1, const float* __restrict__ W2,
                              const float* __restrict__ Wr, const float* __restrict__ Wmu,
                              const float* __restrict__ Wls,
                              unsigned short* __restrict__ W1t, unsigned short* __restrict__ W2t,
                              unsigned short* __restrict__ Wrt, unsigned short* __restrict__ Wmlt){
  int b = blockIdx.x, t = threadIdx.x;
  for (int it = 0; it < 64; it++){
    int idx = it*256 + t;          // 16384 entries
    int k = idx >> 7, c = idx & 127;
    float v; unsigned short* dst;
    if (b == 0){ v = W1[k*128+c]; dst = W1t; }
    else if (b == 1){ v = W2[k*128+c]; dst = W2t; }
    else if (b == 2){ v = Wr[k*128+c]; dst = Wrt; }
    else { v = (c & 1) ? Wls[k*64 + (c>>1)] : Wmu[k*64 + (c>>1)]; dst = Wmlt; }
    dst[c*128 + k] = f2bf(v);      // [col][k]
  }
}

__global__ void wvec_kernel(const float* __restrict__ We2, const float* __restrict__ ae2,
                            const float* __restrict__ Wemu, const float* __restrict__ aemu,
                            const float* __restrict__ Wels, const float* __restrict__ aels,
                            float* __restrict__ wv){
  int t = threadIdx.x;
  if (t < 16){
    float s = 0.f; for (int c = 0; c < 128; c++) s += We2[t*128+c]*ae2[c];
    wv[t] = s;
  } else if (t < 32){
    int k = t-16; float s = 0.f; for (int c = 0; c < 64; c++) s += Wemu[k*64+c]*aemu[c];
    wv[16+k] = s;
  } else if (t < 48){
    int k = t-32; float s = 0.f; for (int c = 0; c < 64; c++) s += Wels[k*64+c]*aels[c];
    wv[32+k] = s;
  }
}

__global__ void cast_x_kernel(const float* __restrict__ x, unsigned short* __restrict__ Xb){
  int i = blockIdx.x*256 + threadIdx.x;   // 8 elems each
  if (i >= NN*128/8) return;
  const float4* src = (const float4*)x + (size_t)i*2;
  float4 v0 = src[0], v1 = src[1];
  ushort4 o0 = make_ushort4(f2bf(v0.x), f2bf(v0.y), f2bf(v0.z), f2bf(v0.w));
  ushort4 o1 = make_ushort4(f2bf(v1.x), f2bf(v1.y), f2bf(v1.z), f2bf(v1.w));
  *(ushort4*)(Xb + (size_t)i*8)     = o0;
  *(ushort4*)(Xb + (size_t)i*8 + 4) = o1;
}

// ---- per-edge attention scalars: ew3[e] = {s2, smu, sls, pad} ----
__global__ void edge_scalar_kernel(const float* __restrict__ ea, const float* __restrict__ wv,
                                   float4* __restrict__ ew3){
  int e = blockIdx.x*256 + threadIdx.x;
  if (e >= NE) return;
  const float4* p = (const float4*)(ea + (size_t)e*16);
  float a[16]; float4 v;
  v = p[0]; a[0]=v.x; a[1]=v.y; a[2]=v.z; a[3]=v.w;
  v = p[1]; a[4]=v.x; a[5]=v.y; a[6]=v.z; a[7]=v.w;
  v = p[2]; a[8]=v.x; a[9]=v.y; a[10]=v.z; a[11]=v.w;
  v = p[3]; a[12]=v.x; a[13]=v.y; a[14]=v.z; a[15]=v.w;
  float s2 = 0.f, smu = 0.f, sls = 0.f;
  #pragma unroll
  for (int k = 0; k < 16; k++){
    s2  = fmaf(a[k], wv[k],    s2);
    smu = fmaf(a[k], wv[16+k], smu);
    sls = fmaf(a[k], wv[32+k], sls);
  }
  ew3[e] = make_float4(s2, smu, sls, 0.f);
}

__global__ void zero_kernel(int* __restrict__ p, int n){
  int i = blockIdx.x*256 + threadIdx.x;
  if (i < n) p[i] = 0;
}

// ---- coarse 256-bucket histogram of dst>>9 (LDS aggregated) ----
__global__ __launch_bounds__(1024) void ehist_kernel(const int* __restrict__ ei,
                                                     unsigned* __restrict__ gbcnt){
  __shared__ unsigned h[256];
  int t = threadIdx.x;
  if (t < 256) h[t] = 0;
  __syncthreads();
  int e0 = blockIdx.x*4096 + t;
  #pragma unroll
  for (int k = 0; k < 4; k++){
    int e = e0 + k*1024;
    if (e < NE) atomicAdd(&h[ei[NE+e] >> BSH], 1);
  }
  __syncthreads();
  if (t < 256 && h[t]) atomicAdd(&gbcnt[t], h[t]);
}

__global__ void bscan_kernel(const unsigned* __restrict__ gbcnt,
                             unsigned* __restrict__ gbbase, int* __restrict__ rowptr){
  __shared__ unsigned sh[256];
  int t = threadIdx.x;   // 256
  unsigned v = gbcnt[t];
  sh[t] = v; __syncthreads();
  for (int o = 1; o < 256; o <<= 1){
    unsigned add = (t >= o) ? sh[t-o] : 0;
    __syncthreads();
    sh[t] += add;
    __syncthreads();
  }
  gbbase[t+1] = sh[t];
  if (t == 0){ gbbase[0] = 0; rowptr[NN] = NE; }
}

// ---- bin: append {dst,u} + {s2,smu,sls} to per-bucket regions (L2-hot, sequential) ----
__global__ __launch_bounds__(1024) void bin_kernel(const int* __restrict__ ei,
                                                   const float4* __restrict__ ew3,
                                                   const unsigned* __restrict__ gbbase,
                                                   unsigned* __restrict__ gbfill,
                                                   uint2* __restrict__ bdu,
                                                   float4* __restrict__ bw){
  __shared__ unsigned hcnt[256], hbase[256], hcur[256];
  int t = threadIdx.x;
  if (t < 256){ hcnt[t] = 0; hcur[t] = 0; }
  __syncthreads();
  int d[4], u[4], b[4]; float4 w[4]; bool val[4];
  int e0 = blockIdx.x*4096 + t;
  #pragma unroll
  for (int k = 0; k < 4; k++){
    int e = e0 + k*1024;
    val[k] = e < NE;
    if (val[k]){
      d[k] = ei[NE+e]; u[k] = ei[e]; w[k] = ew3[e];
      b[k] = d[k] >> BSH;
      atomicAdd(&hcnt[b[k]], 1);
    }
  }
  __syncthreads();
  if (t < 256){
    unsigned c = hcnt[t];
    hbase[t] = c ? atomicAdd(&gbfill[t], c) : 0u;
  }
  __syncthreads();
  #pragma unroll
  for (int k = 0; k < 4; k++){
    if (val[k]){
      unsigned pos = atomicAdd(&hcur[b[k]], 1);
      unsigned slot = gbbase[b[k]] + hbase[b[k]] + pos;
      bdu[slot] = make_uint2((unsigned)d[k], (unsigned)u[k]);
      bw[slot]  = w[k];
    }
  }
}

// ---- place: per-bucket sub-rowptr in LDS + scatter into L2-resident 65KB CSR region ----
__global__ __launch_bounds__(1024) void place_kernel(const uint2* __restrict__ bdu,
                                                     const float4* __restrict__ bw,
                                                     const unsigned* __restrict__ gbbase,
                                                     int* __restrict__ rowptr,
                                                     unsigned* __restrict__ csr_u,
                                                     float* __restrict__ ewp2,
                                                     float2* __restrict__ ewpmuls){
  __shared__ unsigned h[512], incl[512], cur[512];
  int b = blockIdx.x, t = threadIdx.x;
  unsigned cbase = gbbase[b];
  unsigned cnt = gbbase[b+1] - cbase;
  if (t < 512) h[t] = 0;
  __syncthreads();
  for (unsigned i = t; i < cnt; i += 1024)
    atomicAdd(&h[bdu[cbase+i].x & 511], 1);
  __syncthreads();
  if (t < 512) incl[t] = h[t];
  __syncthreads();
  for (int o = 1; o < 512; o <<= 1){
    unsigned add = (t >= o && t < 512) ? incl[t-o] : 0;
    __syncthreads();
    if (t < 512) incl[t] += add;
    __syncthreads();
  }
  if (t < 512){
    cur[t] = 0;
    int node = (b << BSH) + t;
    if (node < NN) rowptr[node] = (int)(cbase + incl[t] - h[t]);
  }
  __syncthreads();
  for (unsigned i = t; i < cnt; i += 1024){
    uint2 du = bdu[cbase+i];
    unsigned ld = du.x & 511;
    unsigned pos = atomicAdd(&cur[ld], 1);
    unsigned slot = cbase + (incl[ld] - h[ld]) + pos;
    float4 w = bw[cbase+i];
    csr_u[slot] = du.y;
    ewp2[slot] = w.x;
    ewpmuls[slot] = make_float2(w.y, w.z);
  }
}

// ---- MFMA GEMM: Y[nrows x 128] = Xb[nrows x 128] @ Wt^T, bf16 in, fp32 acc ----
template<bool OUTF32>
__global__ __launch_bounds__(256) void gemm_bf16(const unsigned short* __restrict__ Xb,
                                                 const unsigned short* __restrict__ Wt,
                                                 void* __restrict__ Y,
                                                 const float* __restrict__ bias, int nrows){
  __shared__ uint4 As[128*16];   // 32 KB, XOR-swizzled chunks
  __shared__ uint4 Bs[128*16];   // 32 KB
  int t = threadIdx.x;
  int row0 = blockIdx.x * 128;
  #pragma unroll
  for (int p = 0; p < 8; p++){
    int idx = p*256 + t;
    int r = idx >> 4, cir = idx & 15;
    uint4 v = make_uint4(0,0,0,0);
    if (row0 + r < nrows) v = *(const uint4*)(Xb + ((size_t)(row0+r))*128 + cir*8);
    As[r*16 + (cir ^ (r & 7))] = v;
  }
  #pragma unroll
  for (int p = 0; p < 8; p++){
    int idx = p*256 + t;
    int r = idx >> 4, cir = idx & 15;
    Bs[r*16 + (cir ^ (r & 7))] = *(const uint4*)(Wt + (size_t)r*128 + cir*8);
  }
  __syncthreads();
  int w = t >> 6, l = t & 63;
  int lr = l & 15;
  int lk = l >> 4;
  const bf16x8* As8 = (const bf16x8*)As;
  const bf16x8* Bs8 = (const bf16x8*)Bs;
  f32x4 acc[2][8];
  f32x4 zero = {0.f, 0.f, 0.f, 0.f};
  #pragma unroll
  for (int m = 0; m < 2; m++)
    #pragma unroll
    for (int n = 0; n < 8; n++) acc[m][n] = zero;
  #pragma unroll
  for (int ks = 0; ks < 4; ks++){
    bf16x8 a0, a1, bf[8];
    { int r = w*32 + lr;      a0 = As8[r*16 + ((ks*4+lk) ^ (r&7))]; }
    { int r = w*32 + 16 + lr; a1 = As8[r*16 + ((ks*4+lk) ^ (r&7))]; }
    #pragma unroll
    for (int nt = 0; nt < 8; nt++){
      int r = nt*16 + lr;
      bf[nt] = Bs8[r*16 + ((ks*4+lk) ^ (r&7))];
    }
    #pragma unroll
    for (int nt = 0; nt < 8; nt++){
      acc[0][nt] = __builtin_amdgcn_mfma_f32_16x16x32_bf16(a0, bf[nt], acc[0][nt], 0, 0, 0);
      acc[1][nt] = __builtin_amdgcn_mfma_f32_16x16x32_bf16(a1, bf[nt], acc[1][nt], 0, 0, 0);
    }
  }
  #pragma unroll
  for (int mt = 0; mt < 2; mt++){
    int gr0 = row0 + w*32 + mt*16 + lk*4;
    #pragma unroll
    for (int nt = 0; nt < 8; nt++){
      int col = nt*16 + lr;
      float bv = OUTF32 ? bias[col] : 0.f;
      #pragma unroll
      for (int i = 0; i < 4; i++){
        int r = gr0 + i;
        if (r < nrows){
          float o = acc[mt][nt][i];
          if constexpr (OUTF32) ((float*)Y)[(size_t)r*128 + col] = o + bv;
          else ((unsigned short*)Y)[(size_t)r*128 + col] = f2bf(o);
        }
      }
    }
  }
}

// ---- per-node dots on bf16 H (C=128) ----
__global__ __launch_bounds__(256) void dots_kernel(const unsigned short* __restrict__ Hb,
                                                   const float* __restrict__ asrc,
                                                   const float* __restrict__ adst,
                                                   float* __restrict__ s, float* __restrict__ d){
  int n = (blockIdx.x * blockDim.x + threadIdx.x) >> 6;
  int lane = threadIdx.x & 63;
  if (n >= NN) return;
  ushort2 q = *(const ushort2*)(Hb + (size_t)n*128 + lane*2);
  float h0 = bf2f(q.x), h1 = bf2f(q.y);
  float ps = h0*asrc[lane*2] + h1*asrc[lane*2+1];
  float pd = h0*adst[lane*2] + h1*adst[lane*2+1];
  ps = wave_sum(ps); pd = wave_sum(pd);
  if (lane == 0){ s[n] = ps; d[n] = pd; }
}

// ---- fused mu/ls dots on interleaved Y [mu0,ls0,mu1,ls1,...] ----
__global__ __launch_bounds__(256) void dots_muls_kernel(const unsigned short* __restrict__ Yb,
                                                        const float* __restrict__ amus,
                                                        const float* __restrict__ amud,
                                                        const float* __restrict__ alss,
                                                        const float* __restrict__ alsd,
                                                        float2* __restrict__ sg,
                                                        float2* __restrict__ dg){
  int n = (blockIdx.x * blockDim.x + threadIdx.x) >> 6;
  int lane = threadIdx.x & 63;
  if (n >= NN) return;
  ushort2 q = *(const ushort2*)(Yb + (size_t)n*128 + lane*2);
  float hmu = bf2f(q.x), hls = bf2f(q.y);
  float smu = wave_sum(hmu * amus[lane]);
  float dmu = wave_sum(hmu * amud[lane]);
  float sls = wave_sum(hls * alss[lane]);
  float dls = wave_sum(hls * alsd[lane]);
  if (lane == 0){ sg[n] = make_float2(smu, sls); dg[n] = make_float2(dmu, dls); }
}

// ---- conv aggregation: C=128, sequential csr_u/ewp, gather unrolled x8 ----
template<bool HAS_EW>
__global__ __launch_bounds__(256) void agg_conv(const unsigned short* __restrict__ Hb,
                                                const float* __restrict__ s,
                                                const float* __restrict__ dsc,
                                                const float* __restrict__ ewp,
                                                const int* __restrict__ rowptr,
                                                const unsigned* __restrict__ csr_u,
                                                const float* __restrict__ bias,
                                                const float* __restrict__ resid,
                                                unsigned short* __restrict__ out){
  int v = (blockIdx.x * blockDim.x + threadIdx.x) >> 6;
  int lane = threadIdx.x & 63;
  if (v >= NN) return;
  int rs = rowptr[v], re = rowptr[v+1];
  int deg = re - rs;
  float d_v = dsc[v];
  float pl = 0.f, acc0 = 0.f, acc1 = 0.f, ewl = 0.f;
  for (int base = rs; base < re; base += 64){
    int i = base + lane;
    int u = 0; float w = 0.f;
    if (i < re){
      u = (int)csr_u[i];
      float e = HAS_EW ? ewp[i] : 0.f;
      if (HAS_EW) ewl += e;
      float a = s[u] + d_v + e;
      float l = a > 0.f ? a : 0.2f*a;
      w = __expf(l);
    }
    pl += w;
    int nv = re - base; if (nv > 64) nv = 64;
    int j = 0;
    for (; j + 8 <= nv; j += 8){
      ushort2 q[8];
      float wj[8];
      #pragma unroll
      for (int k = 0; k < 8; k++){
        int uk = __builtin_amdgcn_readlane(u, j+k);
        wj[k] = rl_f(w, j+k);
        q[k] = *(const ushort2*)(Hb + (size_t)uk*128 + lane*2);
      }
      #pragma unroll
      for (int k = 0; k < 8; k++){
        acc0 = fmaf(wj[k], bf2f(q[k].x), acc0);
        acc1 = fmaf(wj[k], bf2f(q[k].y), acc1);
      }
    }
    for (; j < nv; j++){
      int uu = __builtin_amdgcn_readlane(u, j);
      float ww = rl_f(w, j);
      ushort2 q = *(const ushort2*)(Hb + (size_t)uu*128 + lane*2);
      acc0 = fmaf(ww, bf2f(q.x), acc0); acc1 = fmaf(ww, bf2f(q.y), acc1);
    }
  }
  float p = wave_sum(pl);
  float ews = HAS_EW ? wave_sum(ewl) : 0.f;
  float selfa = s[v] + d_v + (HAS_EW ? ews / (float)(deg > 1 ? deg : 1) : 0.f);
  float lself = selfa > 0.f ? selfa : 0.2f*selfa;
  float wself = __expf(lself);
  p += wself;
  {
    ushort2 q = *(const ushort2*)(Hb + (size_t)v*128 + lane*2);
    acc0 = fmaf(wself, bf2f(q.x), acc0);
    acc1 = fmaf(wself, bf2f(q.y), acc1);
  }
  float inv = 1.f / p;
  int c0 = lane*2;
  float o0 = acc0*inv + bias[c0], o1 = acc1*inv + bias[c0+1];
  o0 = fmaxf(o0, 0.f); o1 = fmaxf(o1, 0.f);
  if (HAS_EW){
    o0 += resid[(size_t)v*128 + c0];
    o1 += resid[(size_t)v*128 + c0 + 1];
  }
  *(ushort2*)(out + (size_t)v*128 + c0) = make_ushort2(f2bf(o0), f2bf(o1));
}

// ---- fused mu+ls aggregation on interleaved Y, sequential ewpmuls, unrolled x8 ----
__global__ __launch_bounds__(256) void agg_muls(const unsigned short* __restrict__ Yb,
                                                const float2* __restrict__ sg,
                                                const float2* __restrict__ dg,
                                                const float2* __restrict__ ewpmuls,
                                                const int* __restrict__ rowptr,
                                                const unsigned* __restrict__ csr_u,
                                                const float* __restrict__ bmu,
                                                const float* __restrict__ bls,
                                                float* __restrict__ outmu,
                                                float* __restrict__ outls){
  int v = (blockIdx.x * blockDim.x + threadIdx.x) >> 6;
  int lane = threadIdx.x & 63;
  if (v >= NN) return;
  int rs = rowptr[v], re = rowptr[v+1];
  int deg = re - rs;
  float2 dv = dg[v];
  float pmu = 0.f, pls = 0.f, accmu = 0.f, accls = 0.f, ewlmu = 0.f, ewlls = 0.f;
  for (int base = rs; base < re; base += 64){
    int i = base + lane;
    int u = 0; float wmu = 0.f, wls = 0.f;
    if (i < re){
      u = (int)csr_u[i];
      float2 su = sg[u];
      float2 ee = ewpmuls[i];
      ewlmu += ee.x; ewlls += ee.y;
      float amu = su.x + dv.x + ee.x;
      float als = su.y + dv.y + ee.y;
      float lmu = amu > 0.f ? amu : 0.2f*amu;
      float lls = als > 0.f ? als : 0.2f*als;
      wmu = __expf(lmu); wls = __expf(lls);
    }
    pmu += wmu; pls += wls;
    int nv = re - base; if (nv > 64) nv = 64;
    int j = 0;
    for (; j + 8 <= nv; j += 8){
      ushort2 q[8];
      float wm[8], wl[8];
      #pragma unroll
      for (int k = 0; k < 8; k++){
        int uk = __builtin_amdgcn_readlane(u, j+k);
        wm[k] = rl_f(wmu, j+k);
        wl[k] = rl_f(wls, j+k);
        q[k] = *(const ushort2*)(Yb + (size_t)uk*128 + lane*2);
      }
      #pragma unroll
      for (int k = 0; k < 8; k++){
        accmu = fmaf(wm[k], bf2f(q[k].x), accmu);
        accls = fmaf(wl[k], bf2f(q[k].y), accls);
      }
    }
    for (; j < nv; j++){
      int uu = __builtin_amdgcn_readlane(u, j);
      float wmj = rl_f(wmu, j), wlj = rl_f(wls, j);
      ushort2 q = *(const ushort2*)(Yb + (size_t)uu*128 + lane*2);
      accmu = fmaf(wmj, bf2f(q.x), accmu);
      accls = fmaf(wlj, bf2f(q.y), accls);
    }
  }
  float Pmu = wave_sum(pmu), Pls = wave_sum(pls);
  float Emu = wave_sum(ewlmu), Els = wave_sum(ewlls);
  float2 sv = sg[v];
  float dnm = (float)(deg > 1 ? deg : 1);
  float selfmu = sv.x + dv.x + Emu/dnm;
  float selfls = sv.y + dv.y + Els/dnm;
  float lmu = selfmu > 0.f ? selfmu : 0.2f*selfmu;
  float lls = selfls > 0.f ? selfls : 0.2f*selfls;
  float wmu_s = __expf(lmu), wls_s = __expf(lls);
  Pmu += wmu_s; Pls += wls_s;
  {
    ushort2 q = *(const ushort2*)(Yb + (size_t)v*128 + lane*2);
    accmu = fmaf(wmu_s, bf2f(q.x), accmu);
    accls = fmaf(wls_s, bf2f(q.y), accls);
  }
  outmu[(size_t)v*64 + lane] = accmu/Pmu + bmu[lane];
  outls[(size_t)v*64 + lane] = accls/Pls + bls[lane];
}

extern "C" void kernel_launch(void* const* d_in, const int* in_sizes, int n_in,
                              void* d_out, int out_size, void* d_ws, size_t ws_size,
                              hipStream_t stream){
  const float* x    = (const float*)d_in[0];
  const int*   ei   = (const int*)  d_in[1];
  const float* ea   = (const float*)d_in[2];
  const float* W1   = (const float*)d_in[3];
  const float* a1s  = (const float*)d_in[4];
  const float* a1d  = (const float*)d_in[5];
  const float* b1   = (const float*)d_in[6];
  const float* W2   = (const float*)d_in[7];
  const float* a2s  = (const float*)d_in[8];
  const float* a2d  = (const float*)d_in[9];
  const float* b2   = (const float*)d_in[10];
  const float* We2  = (const float*)d_in[11];
  const float* ae2  = (const float*)d_in[12];
  const float* Wr   = (const float*)d_in[13];
  const float* br   = (const float*)d_in[14];
  const float* Wmu  = (const float*)d_in[15];
  const float* amus = (const float*)d_in[16];
  const float* amud = (const float*)d_in[17];
  const float* bmu  = (const float*)d_in[18];
  const float* Wemu = (const float*)d_in[19];
  const float* aemu = (const float*)d_in[20];
  const float* Wls  = (const float*)d_in[21];
  const float* alss = (const float*)d_in[22];
  const float* alsd = (const float*)d_in[23];
  const float* bls  = (const float*)d_in[24];
  const float* Wels = (const float*)d_in[25];
  const float* aels = (const float*)d_in[26];

  char* base = (char*)d_ws;
  size_t off = 0;
  auto alloc = [&](size_t bytes)->char*{
    char* p = base + off;
    off = (off + bytes + 511) & ~(size_t)511;
    return p;
  };
  float4*   ew3    = (float4*)alloc((size_t)NE*16);
  int*      rowptr = (int*)   alloc((size_t)(NN+1)*4);
  unsigned* gbcnt  = (unsigned*)alloc(512*4);        // gbcnt[256] + gbfill[256]
  unsigned* gbfill = gbcnt + 256;
  unsigned* gbbase = (unsigned*)alloc(257*4);
  uint2*    bdu    = (uint2*) alloc((size_t)NE*8);
  float4*   bw     = (float4*)alloc((size_t)NE*16);
  unsigned* csr_u  = (unsigned*)alloc((size_t)NE*4);
  float*    ewp2   = (float*) alloc((size_t)NE*4);
  float2*   ewpmls = (float2*)alloc((size_t)NE*8);
  float*    wv     = (float*) alloc(48*4);
  float*    s1     = (float*) alloc((size_t)NN*4);
  float*    d1     = (float*) alloc((size_t)NN*4);
  float2*   sg2    = (float2*)alloc((size_t)NN*8);
  float2*   dg2    = (float2*)alloc((size_t)NN*8);
  unsigned short* W1t  = (unsigned short*)alloc(128*128*2);
  unsigned short* W2t  = (unsigned short*)alloc(128*128*2);
  unsigned short* Wrt  = (unsigned short*)alloc(128*128*2);
  unsigned short* Wmlt = (unsigned short*)alloc(128*128*2);
  unsigned short* Xb   = (unsigned short*)alloc((size_t)NN*128*2);
  unsigned short* bufA = (unsigned short*)alloc((size_t)NN*128*2);  // H1 -> H2 -> Y(muls)
  unsigned short* bufB = (unsigned short*)alloc((size_t)NN*128*2);  // h1 -> h
  if (off > ws_size) return;

  float* outF = (float*)d_out;   // XR (fp32 [NN][128]) then [mu | logstd]
  float* muO  = outF;
  float* lsO  = outF + (size_t)NN*64;

  const int EB  = (NE + 255)/256;
  const int HB  = (NE + 4095)/4096;    // 1024-thread, 4 edges/thread
  const int WB  = (NN*64 + 255)/256;
  const int GB  = (NN + 127)/128;
  const int CB  = (NN*128/8 + 255)/256;

  // precompute + graph build
  prep_w_kernel<<<4, 256, 0, stream>>>(W1, W2, Wr, Wmu, Wls, W1t, W2t, Wrt, Wmlt);
  wvec_kernel<<<1, 64, 0, stream>>>(We2, ae2, Wemu, aemu, Wels, aels, wv);
  cast_x_kernel<<<CB, 256, 0, stream>>>(x, Xb);
  edge_scalar_kernel<<<EB, 256, 0, stream>>>(ea, wv, ew3);
  zero_kernel<<<2, 256, 0, stream>>>((int*)gbcnt, 512);
  ehist_kernel<<<HB, 1024, 0, stream>>>(ei, gbcnt);
  bscan_kernel<<<1, 256, 0, stream>>>(gbcnt, gbbase, rowptr);
  bin_kernel<<<HB, 1024, 0, stream>>>(ei, ew3, gbbase, gbfill, bdu, bw);
  place_kernel<<<NBUK, 1024, 0, stream>>>(bdu, bw, gbbase, rowptr, csr_u, ewp2, ewpmls);

  // conv1
  gemm_bf16<false><<<GB, 256, 0, stream>>>(Xb, W1t, bufA, nullptr, NN);           // H1
  dots_kernel<<<WB, 256, 0, stream>>>(bufA, a1s, a1d, s1, d1);
  agg_conv<false><<<WB, 256, 0, stream>>>(bufA, s1, d1, nullptr, rowptr, csr_u,
                                          b1, nullptr, bufB);                     // h1
  // conv2 + residual
  gemm_bf16<false><<<GB, 256, 0, stream>>>(bufB, W2t, bufA, nullptr, NN);         // H2
  dots_kernel<<<WB, 256, 0, stream>>>(bufA, a2s, a2d, s1, d1);
  gemm_bf16<true><<<GB, 256, 0, stream>>>(Xb, Wrt, outF, br, NN);                 // XR -> d_out
  agg_conv<true><<<WB, 256, 0, stream>>>(bufA, s1, d1, ewp2, rowptr, csr_u,
                                         b2, outF, bufB);                         // h
  // mu + logstd (fused, interleaved)
  gemm_bf16<false><<<GB, 256, 0, stream>>>(bufB, Wmlt, bufA, nullptr, NN);        // Y interleaved
  dots_muls_kernel<<<WB, 256, 0, stream>>>(bufA, amus, amud, alss, alsd, sg2, dg2);
  agg_muls<<<WB, 256, 0, stream>>>(bufA, sg2, dg2, ewpmls, rowptr, csr_u,
                                   bmu, bls, muO, lsO);
}

// Round 6
// 490.603 us; speedup vs baseline: 2.6813x; 1.0513x over previous
//
#include <hip/hip_runtime.h>

#define NN 100000
#define NE 1600000
#define BSH 9
#define NBUK 196          // ceil(NN / 512)

typedef __attribute__((ext_vector_type(8))) short bf16x8;
typedef __attribute__((ext_vector_type(4))) float f32x4;

__device__ __forceinline__ float wave_sum(float v){
  #pragma unroll
  for (int o = 32; o; o >>= 1) v += __shfl_xor(v, o, 64);
  return v;
}
__device__ __forceinline__ float grp_sum16(float v){
  #pragma unroll
  for (int o = 8; o; o >>= 1) v += __shfl_xor(v, o, 16);
  return v;
}
__device__ __forceinline__ float bf2f(unsigned short x){
  return __uint_as_float(((unsigned)x) << 16);
}
__device__ __forceinline__ unsigned short f2bf(float f){
  unsigned u = __float_as_uint(f);
  return (unsigned short)((u + 0x7FFFu + ((u >> 16) & 1u)) >> 16);
}

// ---- weight prep: transpose + bf16. Wmlt interleaved: col 2c=Wmu[:,c], 2c+1=Wls[:,c] ----
__global__ void prep_w_kernel(const float* __restrict__ W1, const float* __restrict__ W2,
                              const float* __restrict__ Wr, const float* __restrict__ Wmu,
                              const float* __restrict__ Wls,
                              unsigned short* __restrict__ W1t, unsigned short* __restrict__ W2t,
                              unsigned short* __restrict__ Wrt, unsigned short* __restrict__ Wmlt){
  int b = blockIdx.x, t = threadIdx.x;
  for (int it = 0; it < 64; it++){
    int idx = it*256 + t;          // 16384 entries
    int k = idx >> 7, c = idx & 127;
    float v; unsigned short* dst;
    if (b == 0){ v = W1[k*128+c]; dst = W1t; }
    else if (b == 1){ v = W2[k*128+c]; dst = W2t; }
    else if (b == 2){ v = Wr[k*128+c]; dst = Wrt; }
    else { v = (c & 1) ? Wls[k*64 + (c>>1)] : Wmu[k*64 + (c>>1)]; dst = Wmlt; }
    dst[c*128 + k] = f2bf(v);      // [col][k]
  }
}

__global__ void wvec_kernel(const float* __restrict__ We2, const float* __restrict__ ae2,
                            const float* __restrict__ Wemu, const float* __restrict__ aemu,
                            const float* __restrict__ Wels, const float* __restrict__ aels,
                            float* __restrict__ wv){
  int t = threadIdx.x;
  if (t < 16){
    float s = 0.f; for (int c = 0; c < 128; c++) s += We2[t*128+c]*ae2[c];
    wv[t] = s;
  } else if (t < 32){
    int k = t-16; float s = 0.f; for (int c = 0; c < 64; c++) s += Wemu[k*64+c]*aemu[c];
    wv[16+k] = s;
  } else if (t < 48){
    int k = t-32; float s = 0.f; for (int c = 0; c < 64; c++) s += Wels[k*64+c]*aels[c];
    wv[32+k] = s;
  }
}

__global__ void cast_x_kernel(const float* __restrict__ x, unsigned short* __restrict__ Xb){
  int i = blockIdx.x*256 + threadIdx.x;   // 8 elems each
  if (i >= NN*128/8) return;
  const float4* src = (const float4*)x + (size_t)i*2;
  float4 v0 = src[0], v1 = src[1];
  ushort4 o0 = make_ushort4(f2bf(v0.x), f2bf(v0.y), f2bf(v0.z), f2bf(v0.w));
  ushort4 o1 = make_ushort4(f2bf(v1.x), f2bf(v1.y), f2bf(v1.z), f2bf(v1.w));
  *(ushort4*)(Xb + (size_t)i*8)     = o0;
  *(ushort4*)(Xb + (size_t)i*8 + 4) = o1;
}

__global__ void zero_kernel(int* __restrict__ p, int n){
  int i = blockIdx.x*256 + threadIdx.x;
  if (i < n) p[i] = 0;
}

// ---- coarse 256-bucket histogram of dst>>9 (LDS aggregated) ----
__global__ __launch_bounds__(1024) void ehist_kernel(const int* __restrict__ ei,
                                                     unsigned* __restrict__ gbcnt){
  __shared__ unsigned h[256];
  int t = threadIdx.x;
  if (t < 256) h[t] = 0;
  __syncthreads();
  int e0 = blockIdx.x*4096 + t;
  #pragma unroll
  for (int k = 0; k < 4; k++){
    int e = e0 + k*1024;
    if (e < NE) atomicAdd(&h[ei[NE+e] >> BSH], 1);
  }
  __syncthreads();
  if (t < 256 && h[t]) atomicAdd(&gbcnt[t], h[t]);
}

__global__ void bscan_kernel(const unsigned* __restrict__ gbcnt,
                             unsigned* __restrict__ gbbase, int* __restrict__ rowptr){
  __shared__ unsigned sh[256];
  int t = threadIdx.x;   // 256
  unsigned v = gbcnt[t];
  sh[t] = v; __syncthreads();
  for (int o = 1; o < 256; o <<= 1){
    unsigned add = (t >= o) ? sh[t-o] : 0;
    __syncthreads();
    sh[t] += add;
    __syncthreads();
  }
  gbbase[t+1] = sh[t];
  if (t == 0){ gbbase[0] = 0; rowptr[NN] = NE; }
}

// ---- bin (+fused edge-scalar dots): append {dst,u} + {s2,smu,sls} per bucket ----
__global__ __launch_bounds__(1024) void bin_kernel(const int* __restrict__ ei,
                                                   const float* __restrict__ ea,
                                                   const float* __restrict__ wv,
                                                   const unsigned* __restrict__ gbbase,
                                                   unsigned* __restrict__ gbfill,
                                                   uint2* __restrict__ bdu,
                                                   float4* __restrict__ bw){
  __shared__ unsigned hcnt[256], hbase[256], hcur[256];
  __shared__ float wvs[48];
  int t = threadIdx.x;
  if (t < 256){ hcnt[t] = 0; hcur[t] = 0; }
  else if (t >= 256 && t < 304) wvs[t-256] = wv[t-256];
  __syncthreads();
  int d[4], u[4], b[4]; float4 w[4]; bool val[4];
  int e0 = blockIdx.x*4096 + t;
  #pragma unroll
  for (int k = 0; k < 4; k++){
    int e = e0 + k*1024;
    val[k] = e < NE;
    if (val[k]){
      d[k] = ei[NE+e]; u[k] = ei[e];
      b[k] = d[k] >> BSH;
      atomicAdd(&hcnt[b[k]], 1);
      const float4* p = (const float4*)(ea + (size_t)e*16);
      float a[16]; float4 vv;
      vv = p[0]; a[0]=vv.x; a[1]=vv.y; a[2]=vv.z; a[3]=vv.w;
      vv = p[1]; a[4]=vv.x; a[5]=vv.y; a[6]=vv.z; a[7]=vv.w;
      vv = p[2]; a[8]=vv.x; a[9]=vv.y; a[10]=vv.z; a[11]=vv.w;
      vv = p[3]; a[12]=vv.x; a[13]=vv.y; a[14]=vv.z; a[15]=vv.w;
      float s2 = 0.f, smu = 0.f, sls = 0.f;
      #pragma unroll
      for (int q = 0; q < 16; q++){
        s2  = fmaf(a[q], wvs[q],    s2);
        smu = fmaf(a[q], wvs[16+q], smu);
        sls = fmaf(a[q], wvs[32+q], sls);
      }
      w[k] = make_float4(s2, smu, sls, 0.f);
    }
  }
  __syncthreads();
  if (t < 256){
    unsigned c = hcnt[t];
    hbase[t] = c ? atomicAdd(&gbfill[t], c) : 0u;
  }
  __syncthreads();
  #pragma unroll
  for (int k = 0; k < 4; k++){
    if (val[k]){
      unsigned pos = atomicAdd(&hcur[b[k]], 1);
      unsigned slot = gbbase[b[k]] + hbase[b[k]] + pos;
      bdu[slot] = make_uint2((unsigned)d[k], (unsigned)u[k]);
      bw[slot]  = w[k];
    }
  }
}

// ---- place: per-bucket sub-rowptr in LDS + scatter into L2-resident CSR region ----
__global__ __launch_bounds__(1024) void place_kernel(const uint2* __restrict__ bdu,
                                                     const float4* __restrict__ bw,
                                                     const unsigned* __restrict__ gbbase,
                                                     int* __restrict__ rowptr,
                                                     unsigned* __restrict__ csr_u,
                                                     float* __restrict__ ewp2,
                                                     float2* __restrict__ ewpmuls){
  __shared__ unsigned h[512], incl[512], cur[512];
  int b = blockIdx.x, t = threadIdx.x;
  unsigned cbase = gbbase[b];
  unsigned cnt = gbbase[b+1] - cbase;
  if (t < 512) h[t] = 0;
  __syncthreads();
  for (unsigned i = t; i < cnt; i += 1024)
    atomicAdd(&h[bdu[cbase+i].x & 511], 1);
  __syncthreads();
  if (t < 512) incl[t] = h[t];
  __syncthreads();
  for (int o = 1; o < 512; o <<= 1){
    unsigned add = (t >= o && t < 512) ? incl[t-o] : 0;
    __syncthreads();
    if (t < 512) incl[t] += add;
    __syncthreads();
  }
  if (t < 512){
    cur[t] = 0;
    int node = (b << BSH) + t;
    if (node < NN) rowptr[node] = (int)(cbase + incl[t] - h[t]);
  }
  __syncthreads();
  for (unsigned i = t; i < cnt; i += 1024){
    uint2 du = bdu[cbase+i];
    unsigned ld = du.x & 511;
    unsigned pos = atomicAdd(&cur[ld], 1);
    unsigned slot = cbase + (incl[ld] - h[ld]) + pos;
    float4 w = bw[cbase+i];
    csr_u[slot] = du.y;
    ewp2[slot] = w.x;
    ewpmuls[slot] = make_float2(w.y, w.z);
  }
}

// ---- MFMA GEMM: Y[nrows x 128] = Xb[nrows x 128] @ Wt^T, bf16 in, fp32 acc ----
template<bool OUTF32>
__global__ __launch_bounds__(256) void gemm_bf16(const unsigned short* __restrict__ Xb,
                                                 const unsigned short* __restrict__ Wt,
                                                 void* __restrict__ Y,
                                                 const float* __restrict__ bias, int nrows){
  __shared__ uint4 As[128*16];   // 32 KB, XOR-swizzled chunks
  __shared__ uint4 Bs[128*16];   // 32 KB
  int t = threadIdx.x;
  int row0 = blockIdx.x * 128;
  #pragma unroll
  for (int p = 0; p < 8; p++){
    int idx = p*256 + t;
    int r = idx >> 4, cir = idx & 15;
    uint4 v = make_uint4(0,0,0,0);
    if (row0 + r < nrows) v = *(const uint4*)(Xb + ((size_t)(row0+r))*128 + cir*8);
    As[r*16 + (cir ^ (r & 7))] = v;
  }
  #pragma unroll
  for (int p = 0; p < 8; p++){
    int idx = p*256 + t;
    int r = idx >> 4, cir = idx & 15;
    Bs[r*16 + (cir ^ (r & 7))] = *(const uint4*)(Wt + (size_t)r*128 + cir*8);
  }
  __syncthreads();
  int w = t >> 6, l = t & 63;
  int lr = l & 15;
  int lk = l >> 4;
  const bf16x8* As8 = (const bf16x8*)As;
  const bf16x8* Bs8 = (const bf16x8*)Bs;
  f32x4 acc[2][8];
  f32x4 zero = {0.f, 0.f, 0.f, 0.f};
  #pragma unroll
  for (int m = 0; m < 2; m++)
    #pragma unroll
    for (int n = 0; n < 8; n++) acc[m][n] = zero;
  #pragma unroll
  for (int ks = 0; ks < 4; ks++){
    bf16x8 a0, a1, bf[8];
    { int r = w*32 + lr;      a0 = As8[r*16 + ((ks*4+lk) ^ (r&7))]; }
    { int r = w*32 + 16 + lr; a1 = As8[r*16 + ((ks*4+lk) ^ (r&7))]; }
    #pragma unroll
    for (int nt = 0; nt < 8; nt++){
      int r = nt*16 + lr;
      bf[nt] = Bs8[r*16 + ((ks*4+lk) ^ (r&7))];
    }
    #pragma unroll
    for (int nt = 0; nt < 8; nt++){
      acc[0][nt] = __builtin_amdgcn_mfma_f32_16x16x32_bf16(a0, bf[nt], acc[0][nt], 0, 0, 0);
      acc[1][nt] = __builtin_amdgcn_mfma_f32_16x16x32_bf16(a1, bf[nt], acc[1][nt], 0, 0, 0);
    }
  }
  #pragma unroll
  for (int mt = 0; mt < 2; mt++){
    int gr0 = row0 + w*32 + mt*16 + lk*4;
    #pragma unroll
    for (int nt = 0; nt < 8; nt++){
      int col = nt*16 + lr;
      float bv = OUTF32 ? bias[col] : 0.f;
      #pragma unroll
      for (int i = 0; i < 4; i++){
        int r = gr0 + i;
        if (r < nrows){
          float o = acc[mt][nt][i];
          if constexpr (OUTF32) ((float*)Y)[(size_t)r*128 + col] = o + bv;
          else ((unsigned short*)Y)[(size_t)r*128 + col] = f2bf(o);
        }
      }
    }
  }
}

// ---- per-node dots on bf16 H (C=128) ----
__global__ __launch_bounds__(256) void dots_kernel(const unsigned short* __restrict__ Hb,
                                                   const float* __restrict__ asrc,
                                                   const float* __restrict__ adst,
                                                   float* __restrict__ s, float* __restrict__ d){
  int n = (blockIdx.x * blockDim.x + threadIdx.x) >> 6;
  int lane = threadIdx.x & 63;
  if (n >= NN) return;
  ushort2 q = *(const ushort2*)(Hb + (size_t)n*128 + lane*2);
  float h0 = bf2f(q.x), h1 = bf2f(q.y);
  float ps = h0*asrc[lane*2] + h1*asrc[lane*2+1];
  float pd = h0*adst[lane*2] + h1*adst[lane*2+1];
  ps = wave_sum(ps); pd = wave_sum(pd);
  if (lane == 0){ s[n] = ps; d[n] = pd; }
}

// ---- fused mu/ls dots on interleaved Y [mu0,ls0,mu1,ls1,...] ----
__global__ __launch_bounds__(256) void dots_muls_kernel(const unsigned short* __restrict__ Yb,
                                                        const float* __restrict__ amus,
                                                        const float* __restrict__ amud,
                                                        const float* __restrict__ alss,
                                                        const float* __restrict__ alsd,
                                                        float2* __restrict__ sg,
                                                        float2* __restrict__ dg){
  int n = (blockIdx.x * blockDim.x + threadIdx.x) >> 6;
  int lane = threadIdx.x & 63;
  if (n >= NN) return;
  ushort2 q = *(const ushort2*)(Yb + (size_t)n*128 + lane*2);
  float hmu = bf2f(q.x), hls = bf2f(q.y);
  float smu = wave_sum(hmu * amus[lane]);
  float dmu = wave_sum(hmu * amud[lane]);
  float sls = wave_sum(hls * alss[lane]);
  float dls = wave_sum(hls * alsd[lane]);
  if (lane == 0){ sg[n] = make_float2(smu, sls); dg[n] = make_float2(dmu, dls); }
}

// ---- conv aggregation: 16-lane groups (4 nodes/wave), uint4 (8 col) per lane ----
template<bool HAS_EW>
__global__ __launch_bounds__(256) void agg_conv(const unsigned short* __restrict__ Hb,
                                                const float* __restrict__ s,
                                                const float* __restrict__ dsc,
                                                const float* __restrict__ ewp,
                                                const int* __restrict__ rowptr,
                                                const unsigned* __restrict__ csr_u,
                                                const float* __restrict__ bias,
                                                const float* __restrict__ resid,
                                                unsigned short* __restrict__ out){
  int v = (blockIdx.x * blockDim.x + threadIdx.x) >> 4;
  int lig = threadIdx.x & 15;
  if (v >= NN) return;
  int rs = rowptr[v], re = rowptr[v+1];
  int deg = re - rs;
  float d_v = dsc[v];
  float acc[8] = {0.f,0.f,0.f,0.f,0.f,0.f,0.f,0.f};
  float pl = 0.f, ewl = 0.f;
  for (int base = rs; base < re; base += 16){
    int i = base + lig;
    int u = 0; float w = 0.f;
    if (i < re){
      u = (int)csr_u[i];
      float e = HAS_EW ? ewp[i] : 0.f;
      if (HAS_EW) ewl += e;
      float a = s[u] + d_v + e;
      float l = a > 0.f ? a : 0.2f*a;
      w = __expf(l);
    }
    pl += w;
    int nv = re - base; if (nv > 16) nv = 16;
    int j = 0;
    for (; j + 4 <= nv; j += 4){
      uint4 q[4]; float wj[4];
      #pragma unroll
      for (int k = 0; k < 4; k++){
        int uk = __shfl(u, j+k, 16);
        wj[k] = __shfl(w, j+k, 16);
        q[k] = *(const uint4*)(Hb + (size_t)uk*128 + lig*8);
      }
      #pragma unroll
      for (int k = 0; k < 4; k++){
        const unsigned* qq = (const unsigned*)&q[k];
        #pragma unroll
        for (int c = 0; c < 4; c++){
          acc[2*c]   = fmaf(wj[k], __uint_as_float(qq[c] << 16), acc[2*c]);
          acc[2*c+1] = fmaf(wj[k], __uint_as_float(qq[c] & 0xFFFF0000u), acc[2*c+1]);
        }
      }
    }
    for (; j < nv; j++){
      int uk = __shfl(u, j, 16);
      float wk = __shfl(w, j, 16);
      uint4 q = *(const uint4*)(Hb + (size_t)uk*128 + lig*8);
      const unsigned* qq = (const unsigned*)&q;
      #pragma unroll
      for (int c = 0; c < 4; c++){
        acc[2*c]   = fmaf(wk, __uint_as_float(qq[c] << 16), acc[2*c]);
        acc[2*c+1] = fmaf(wk, __uint_as_float(qq[c] & 0xFFFF0000u), acc[2*c+1]);
      }
    }
  }
  float p = grp_sum16(pl);
  float ews = HAS_EW ? grp_sum16(ewl) : 0.f;
  float selfa = s[v] + d_v + (HAS_EW ? ews / (float)(deg > 1 ? deg : 1) : 0.f);
  float lself = selfa > 0.f ? selfa : 0.2f*selfa;
  float wself = __expf(lself);
  p += wself;
  {
    uint4 q = *(const uint4*)(Hb + (size_t)v*128 + lig*8);
    const unsigned* qq = (const unsigned*)&q;
    #pragma unroll
    for (int c = 0; c < 4; c++){
      acc[2*c]   = fmaf(wself, __uint_as_float(qq[c] << 16), acc[2*c]);
      acc[2*c+1] = fmaf(wself, __uint_as_float(qq[c] & 0xFFFF0000u), acc[2*c+1]);
    }
  }
  float inv = 1.f / p;
  int c0 = lig*8;
  float o[8];
  #pragma unroll
  for (int c = 0; c < 8; c++){
    o[c] = acc[c]*inv + bias[c0+c];
    o[c] = fmaxf(o[c], 0.f);
  }
  if (HAS_EW){
    float4 r0 = *(const float4*)(resid + (size_t)v*128 + c0);
    float4 r1 = *(const float4*)(resid + (size_t)v*128 + c0 + 4);
    o[0]+=r0.x; o[1]+=r0.y; o[2]+=r0.z; o[3]+=r0.w;
    o[4]+=r1.x; o[5]+=r1.y; o[6]+=r1.z; o[7]+=r1.w;
  }
  uint4 ow;
  unsigned* owp = (unsigned*)&ow;
  #pragma unroll
  for (int c = 0; c < 4; c++)
    owp[c] = (unsigned)f2bf(o[2*c]) | ((unsigned)f2bf(o[2*c+1]) << 16);
  *(uint4*)(out + (size_t)v*128 + c0) = ow;
}

// ---- fused mu+ls aggregation: 16-lane groups, interleaved Y, uint4 per lane ----
__global__ __launch_bounds__(256) void agg_muls(const unsigned short* __restrict__ Yb,
                                                const float2* __restrict__ sg,
                                                const float2* __restrict__ dg,
                                                const float2* __restrict__ ewpmuls,
                                                const int* __restrict__ rowptr,
                                                const unsigned* __restrict__ csr_u,
                                                const float* __restrict__ bmu,
                                                const float* __restrict__ bls,
                                                float* __restrict__ outmu,
                                                float* __restrict__ outls){
  int v = (blockIdx.x * blockDim.x + threadIdx.x) >> 4;
  int lig = threadIdx.x & 15;
  if (v >= NN) return;
  int rs = rowptr[v], re = rowptr[v+1];
  int deg = re - rs;
  float2 dv = dg[v];
  float accmu[4] = {0.f,0.f,0.f,0.f}, accls[4] = {0.f,0.f,0.f,0.f};
  float pmu = 0.f, pls = 0.f, ewlmu = 0.f, ewlls = 0.f;
  for (int base = rs; base < re; base += 16){
    int i = base + lig;
    int u = 0; float wmu = 0.f, wls = 0.f;
    if (i < re){
      u = (int)csr_u[i];
      float2 su = sg[u];
      float2 ee = ewpmuls[i];
      ewlmu += ee.x; ewlls += ee.y;
      float amu = su.x + dv.x + ee.x;
      float als = su.y + dv.y + ee.y;
      float lmu = amu > 0.f ? amu : 0.2f*amu;
      float lls = als > 0.f ? als : 0.2f*als;
      wmu = __expf(lmu); wls = __expf(lls);
    }
    pmu += wmu; pls += wls;
    int nv = re - base; if (nv > 16) nv = 16;
    int j = 0;
    for (; j + 4 <= nv; j += 4){
      uint4 q[4]; float wm[4], wl[4];
      #pragma unroll
      for (int k = 0; k < 4; k++){
        int uk = __shfl(u, j+k, 16);
        wm[k] = __shfl(wmu, j+k, 16);
        wl[k] = __shfl(wls, j+k, 16);
        q[k] = *(const uint4*)(Yb + (size_t)uk*128 + lig*8);
      }
      #pragma unroll
      for (int k = 0; k < 4; k++){
        const unsigned* qq = (const unsigned*)&q[k];
        #pragma unroll
        for (int c = 0; c < 4; c++){
          accmu[c] = fmaf(wm[k], __uint_as_float(qq[c] << 16), accmu[c]);
          accls[c] = fmaf(wl[k], __uint_as_float(qq[c] & 0xFFFF0000u), accls[c]);
        }
      }
    }
    for (; j < nv; j++){
      int uk = __shfl(u, j, 16);
      float wmk = __shfl(wmu, j, 16), wlk = __shfl(wls, j, 16);
      uint4 q = *(const uint4*)(Yb + (size_t)uk*128 + lig*8);
      const unsigned* qq = (const unsigned*)&q;
      #pragma unroll
      for (int c = 0; c < 4; c++){
        accmu[c] = fmaf(wmk, __uint_as_float(qq[c] << 16), accmu[c]);
        accls[c] = fmaf(wlk, __uint_as_float(qq[c] & 0xFFFF0000u), accls[c]);
      }
    }
  }
  float Pmu = grp_sum16(pmu), Pls = grp_sum16(pls);
  float Emu = grp_sum16(ewlmu), Els = grp_sum16(ewlls);
  float2 sv = sg[v];
  float dnm = (float)(deg > 1 ? deg : 1);
  float selfmu = sv.x + dv.x + Emu/dnm;
  float selfls = sv.y + dv.y + Els/dnm;
  float lmu = selfmu > 0.f ? selfmu : 0.2f*selfmu;
  float lls = selfls > 0.f ? selfls : 0.2f*selfls;
  float wmu_s = __expf(lmu), wls_s = __expf(lls);
  Pmu += wmu_s; Pls += wls_s;
  {
    uint4 q = *(const uint4*)(Yb + (size_t)v*128 + lig*8);
    const unsigned* qq = (const unsigned*)&q;
    #pragma unroll
    for (int c = 0; c < 4; c++){
      accmu[c] = fmaf(wmu_s, __uint_as_float(qq[c] << 16), accmu[c]);
      accls[c] = fmaf(wls_s, __uint_as_float(qq[c] & 0xFFFF0000u), accls[c]);
    }
  }
  float imu = 1.f/Pmu, ils = 1.f/Pls;
  int c0 = lig*4;
  float4 omu = make_float4(accmu[0]*imu + bmu[c0], accmu[1]*imu + bmu[c0+1],
                           accmu[2]*imu + bmu[c0+2], accmu[3]*imu + bmu[c0+3]);
  float4 ols = make_float4(accls[0]*ils + bls[c0], accls[1]*ils + bls[c0+1],
                           accls[2]*ils + bls[c0+2], accls[3]*ils + bls[c0+3]);
  *(float4*)(outmu + (size_t)v*64 + c0) = omu;
  *(float4*)(outls + (size_t)v*64 + c0) = ols;
}

extern "C" void kernel_launch(void* const* d_in, const int* in_sizes, int n_in,
                              void* d_out, int out_size, void* d_ws, size_t ws_size,
                              hipStream_t stream){
  const float* x    = (const float*)d_in[0];
  const int*   ei   = (const int*)  d_in[1];
  const float* ea   = (const float*)d_in[2];
  const float* W1   = (const float*)d_in[3];
  const float* a1s  = (const float*)d_in[4];
  const float* a1d  = (const float*)d_in[5];
  const float* b1   = (const float*)d_in[6];
  const float* W2   = (const float*)d_in[7];
  const float* a2s  = (const float*)d_in[8];
  const float* a2d  = (const float*)d_in[9];
  const float* b2   = (const float*)d_in[10];
  const float* We2  = (const float*)d_in[11];
  const float* ae2  = (const float*)d_in[12];
  const float* Wr   = (const float*)d_in[13];
  const float* br   = (const float*)d_in[14];
  const float* Wmu  = (const float*)d_in[15];
  const float* amus = (const float*)d_in[16];
  const float* amud = (const float*)d_in[17];
  const float* bmu  = (const float*)d_in[18];
  const float* Wemu = (const float*)d_in[19];
  const float* aemu = (const float*)d_in[20];
  const float* Wls  = (const float*)d_in[21];
  const float* alss = (const float*)d_in[22];
  const float* alsd = (const float*)d_in[23];
  const float* bls  = (const float*)d_in[24];
  const float* Wels = (const float*)d_in[25];
  const float* aels = (const float*)d_in[26];

  char* base = (char*)d_ws;
  size_t off = 0;
  auto alloc = [&](size_t bytes)->char*{
    char* p = base + off;
    off = (off + bytes + 511) & ~(size_t)511;
    return p;
  };
  int*      rowptr = (int*)   alloc((size_t)(NN+1)*4);
  unsigned* gbcnt  = (unsigned*)alloc(512*4);        // gbcnt[256] + gbfill[256]
  unsigned* gbfill = gbcnt + 256;
  unsigned* gbbase = (unsigned*)alloc(257*4);
  uint2*    bdu    = (uint2*) alloc((size_t)NE*8);
  float4*   bw     = (float4*)alloc((size_t)NE*16);
  unsigned* csr_u  = (unsigned*)alloc((size_t)NE*4);
  float*    ewp2   = (float*) alloc((size_t)NE*4);
  float2*   ewpmls = (float2*)alloc((size_t)NE*8);
  float*    wv     = (float*) alloc(48*4);
  float*    s1     = (float*) alloc((size_t)NN*4);
  float*    d1     = (float*) alloc((size_t)NN*4);
  float2*   sg2    = (float2*)alloc((size_t)NN*8);
  float2*   dg2    = (float2*)alloc((size_t)NN*8);
  unsigned short* W1t  = (unsigned short*)alloc(128*128*2);
  unsigned short* W2t  = (unsigned short*)alloc(128*128*2);
  unsigned short* Wrt  = (unsigned short*)alloc(128*128*2);
  unsigned short* Wmlt = (unsigned short*)alloc(128*128*2);
  unsigned short* Xb   = (unsigned short*)alloc((size_t)NN*128*2);
  unsigned short* bufA = (unsigned short*)alloc((size_t)NN*128*2);  // H1 -> H2 -> Y(muls)
  unsigned short* bufB = (unsigned short*)alloc((size_t)NN*128*2);  // h1 -> h
  if (off > ws_size) return;

  float* outF = (float*)d_out;   // XR (fp32 [NN][128]) then [mu | logstd]
  float* muO  = outF;
  float* lsO  = outF + (size_t)NN*64;

  const int HB   = (NE + 4095)/4096;    // 1024-thread, 4 edges/thread
  const int WB   = (NN*64 + 255)/256;   // one 64-lane wave per node
  const int WB16 = (NN*16 + 255)/256;   // one 16-lane group per node
  const int GB   = (NN + 127)/128;
  const int CB   = (NN*128/8 + 255)/256;

  // precompute + graph build
  prep_w_kernel<<<4, 256, 0, stream>>>(W1, W2, Wr, Wmu, Wls, W1t, W2t, Wrt, Wmlt);
  wvec_kernel<<<1, 64, 0, stream>>>(We2, ae2, Wemu, aemu, Wels, aels, wv);
  cast_x_kernel<<<CB, 256, 0, stream>>>(x, Xb);
  zero_kernel<<<2, 256, 0, stream>>>((int*)gbcnt, 512);
  ehist_kernel<<<HB, 1024, 0, stream>>>(ei, gbcnt);
  bscan_kernel<<<1, 256, 0, stream>>>(gbcnt, gbbase, rowptr);
  bin_kernel<<<HB, 1024, 0, stream>>>(ei, ea, wv, gbbase, gbfill, bdu, bw);
  place_kernel<<<NBUK, 1024, 0, stream>>>(bdu, bw, gbbase, rowptr, csr_u, ewp2, ewpmls);

  // conv1
  gemm_bf16<false><<<GB, 256, 0, stream>>>(Xb, W1t, bufA, nullptr, NN);           // H1
  dots_kernel<<<WB, 256, 0, stream>>>(bufA, a1s, a1d, s1, d1);
  agg_conv<false><<<WB16, 256, 0, stream>>>(bufA, s1, d1, nullptr, rowptr, csr_u,
                                            b1, nullptr, bufB);                   // h1
  // conv2 + residual
  gemm_bf16<false><<<GB, 256, 0, stream>>>(bufB, W2t, bufA, nullptr, NN);         // H2
  dots_kernel<<<WB, 256, 0, stream>>>(bufA, a2s, a2d, s1, d1);
  gemm_bf16<true><<<GB, 256, 0, stream>>>(Xb, Wrt, outF, br, NN);                 // XR -> d_out
  agg_conv<true><<<WB16, 256, 0, stream>>>(bufA, s1, d1, ewp2, rowptr, csr_u,
                                           b2, outF, bufB);                       // h
  // mu + logstd (fused, interleaved)
  gemm_bf16<false><<<GB, 256, 0, stream>>>(bufB, Wmlt, bufA, nullptr, NN);        // Y interleaved
  dots_muls_kernel<<<WB, 256, 0, stream>>>(bufA, amus, amud, alss, alsd, sg2, dg2);
  agg_muls<<<WB16, 256, 0, stream>>>(bufA, sg2, dg2, ewpmls, rowptr, csr_u,
                                     bmu, bls, muO, lsO);
}

// Round 7
// 453.120 us; speedup vs baseline: 2.9031x; 1.0827x over previous
//
#include <hip/hip_runtime.h>

#define NN 100000
#define NE 1600000
#define BSH 9
#define NBUK 196          // ceil(NN / 512)

typedef __attribute__((ext_vector_type(8))) short bf16x8;
typedef __attribute__((ext_vector_type(4))) float f32x4;

__device__ __forceinline__ float grp_sum16(float v){
  #pragma unroll
  for (int o = 8; o; o >>= 1) v += __shfl_xor(v, o, 16);
  return v;
}
__device__ __forceinline__ float grp_sum32(float v){
  #pragma unroll
  for (int o = 16; o; o >>= 1) v += __shfl_xor(v, o, 32);
  return v;
}
__device__ __forceinline__ float bf2f(unsigned short x){
  return __uint_as_float(((unsigned)x) << 16);
}
__device__ __forceinline__ unsigned short f2bf(float f){
  unsigned u = __float_as_uint(f);
  return (unsigned short)((u + 0x7FFFu + ((u >> 16) & 1u)) >> 16);
}

// ---- weight prep: transpose + bf16. Wmlt interleaved: col 2c=Wmu[:,c], 2c+1=Wls[:,c] ----
__global__ void prep_w_kernel(const float* __restrict__ W1, const float* __restrict__ W2,
                              const float* __restrict__ Wr, const float* __restrict__ Wmu,
                              const float* __restrict__ Wls,
                              unsigned short* __restrict__ W1t, unsigned short* __restrict__ W2t,
                              unsigned short* __restrict__ Wrt, unsigned short* __restrict__ Wmlt){
  int b = blockIdx.x, t = threadIdx.x;
  for (int it = 0; it < 64; it++){
    int idx = it*256 + t;          // 16384 entries
    int k = idx >> 7, c = idx & 127;
    float v; unsigned short* dst;
    if (b == 0){ v = W1[k*128+c]; dst = W1t; }
    else if (b == 1){ v = W2[k*128+c]; dst = W2t; }
    else if (b == 2){ v = Wr[k*128+c]; dst = Wrt; }
    else { v = (c & 1) ? Wls[k*64 + (c>>1)] : Wmu[k*64 + (c>>1)]; dst = Wmlt; }
    dst[c*128 + k] = f2bf(v);      // [col][k]
  }
}

__global__ void wvec_kernel(const float* __restrict__ We2, const float* __restrict__ ae2,
                            const float* __restrict__ Wemu, const float* __restrict__ aemu,
                            const float* __restrict__ Wels, const float* __restrict__ aels,
                            float* __restrict__ wv){
  int t = threadIdx.x;
  if (t < 16){
    float s = 0.f; for (int c = 0; c < 128; c++) s += We2[t*128+c]*ae2[c];
    wv[t] = s;
  } else if (t < 32){
    int k = t-16; float s = 0.f; for (int c = 0; c < 64; c++) s += Wemu[k*64+c]*aemu[c];
    wv[16+k] = s;
  } else if (t < 48){
    int k = t-32; float s = 0.f; for (int c = 0; c < 64; c++) s += Wels[k*64+c]*aels[c];
    wv[32+k] = s;
  }
}

__global__ void cast_x_kernel(const float* __restrict__ x, unsigned short* __restrict__ Xb){
  int i = blockIdx.x*256 + threadIdx.x;   // 8 elems each
  if (i >= NN*128/8) return;
  const float4* src = (const float4*)x + (size_t)i*2;
  float4 v0 = src[0], v1 = src[1];
  ushort4 o0 = make_ushort4(f2bf(v0.x), f2bf(v0.y), f2bf(v0.z), f2bf(v0.w));
  ushort4 o1 = make_ushort4(f2bf(v1.x), f2bf(v1.y), f2bf(v1.z), f2bf(v1.w));
  *(ushort4*)(Xb + (size_t)i*8)     = o0;
  *(ushort4*)(Xb + (size_t)i*8 + 4) = o1;
}

__global__ void zero_kernel(int* __restrict__ p, int n){
  int i = blockIdx.x*256 + threadIdx.x;
  if (i < n) p[i] = 0;
}

// ---- coarse 256-bucket histogram of dst>>9 (LDS aggregated) ----
__global__ __launch_bounds__(1024) void ehist_kernel(const int* __restrict__ ei,
                                                     unsigned* __restrict__ gbcnt){
  __shared__ unsigned h[256];
  int t = threadIdx.x;
  if (t < 256) h[t] = 0;
  __syncthreads();
  int e0 = blockIdx.x*4096 + t;
  #pragma unroll
  for (int k = 0; k < 4; k++){
    int e = e0 + k*1024;
    if (e < NE) atomicAdd(&h[ei[NE+e] >> BSH], 1);
  }
  __syncthreads();
  if (t < 256 && h[t]) atomicAdd(&gbcnt[t], h[t]);
}

__global__ void bscan_kernel(const unsigned* __restrict__ gbcnt,
                             unsigned* __restrict__ gbbase, int* __restrict__ rowptr){
  __shared__ unsigned sh[256];
  int t = threadIdx.x;   // 256
  unsigned v = gbcnt[t];
  sh[t] = v; __syncthreads();
  for (int o = 1; o < 256; o <<= 1){
    unsigned add = (t >= o) ? sh[t-o] : 0;
    __syncthreads();
    sh[t] += add;
    __syncthreads();
  }
  gbbase[t+1] = sh[t];
  if (t == 0){ gbbase[0] = 0; rowptr[NN] = NE; }
}

// ---- bin (+fused edge-scalar dots): append {dst,u} + {s2,smu,sls} per bucket ----
__global__ __launch_bounds__(1024) void bin_kernel(const int* __restrict__ ei,
                                                   const float* __restrict__ ea,
                                                   const float* __restrict__ wv,
                                                   const unsigned* __restrict__ gbbase,
                                                   unsigned* __restrict__ gbfill,
                                                   uint2* __restrict__ bdu,
                                                   float4* __restrict__ bw){
  __shared__ unsigned hcnt[256], hbase[256], hcur[256];
  __shared__ float wvs[48];
  int t = threadIdx.x;
  if (t < 256){ hcnt[t] = 0; hcur[t] = 0; }
  else if (t >= 256 && t < 304) wvs[t-256] = wv[t-256];
  __syncthreads();
  int d[4], u[4], b[4]; float4 w[4]; bool val[4];
  int e0 = blockIdx.x*4096 + t;
  #pragma unroll
  for (int k = 0; k < 4; k++){
    int e = e0 + k*1024;
    val[k] = e < NE;
    if (val[k]){
      d[k] = ei[NE+e]; u[k] = ei[e];
      b[k] = d[k] >> BSH;
      atomicAdd(&hcnt[b[k]], 1);
      const float4* p = (const float4*)(ea + (size_t)e*16);
      float a[16]; float4 vv;
      vv = p[0]; a[0]=vv.x; a[1]=vv.y; a[2]=vv.z; a[3]=vv.w;
      vv = p[1]; a[4]=vv.x; a[5]=vv.y; a[6]=vv.z; a[7]=vv.w;
      vv = p[2]; a[8]=vv.x; a[9]=vv.y; a[10]=vv.z; a[11]=vv.w;
      vv = p[3]; a[12]=vv.x; a[13]=vv.y; a[14]=vv.z; a[15]=vv.w;
      float s2 = 0.f, smu = 0.f, sls = 0.f;
      #pragma unroll
      for (int q = 0; q < 16; q++){
        s2  = fmaf(a[q], wvs[q],    s2);
        smu = fmaf(a[q], wvs[16+q], smu);
        sls = fmaf(a[q], wvs[32+q], sls);
      }
      w[k] = make_float4(s2, smu, sls, 0.f);
    }
  }
  __syncthreads();
  if (t < 256){
    unsigned c = hcnt[t];
    hbase[t] = c ? atomicAdd(&gbfill[t], c) : 0u;
  }
  __syncthreads();
  #pragma unroll
  for (int k = 0; k < 4; k++){
    if (val[k]){
      unsigned pos = atomicAdd(&hcur[b[k]], 1);
      unsigned slot = gbbase[b[k]] + hbase[b[k]] + pos;
      bdu[slot] = make_uint2((unsigned)d[k], (unsigned)u[k]);
      bw[slot]  = w[k];
    }
  }
}

// ---- place: per-bucket sub-rowptr in LDS + scatter into L2-resident CSR region ----
__global__ __launch_bounds__(1024) void place_kernel(const uint2* __restrict__ bdu,
                                                     const float4* __restrict__ bw,
                                                     const unsigned* __restrict__ gbbase,
                                                     int* __restrict__ rowptr,
                                                     unsigned* __restrict__ csr_u,
                                                     float* __restrict__ ewp2,
                                                     float2* __restrict__ ewpmuls){
  __shared__ unsigned h[512], incl[512], cur[512];
  int b = blockIdx.x, t = threadIdx.x;
  unsigned cbase = gbbase[b];
  unsigned cnt = gbbase[b+1] - cbase;
  if (t < 512) h[t] = 0;
  __syncthreads();
  for (unsigned i = t; i < cnt; i += 1024)
    atomicAdd(&h[bdu[cbase+i].x & 511], 1);
  __syncthreads();
  if (t < 512) incl[t] = h[t];
  __syncthreads();
  for (int o = 1; o < 512; o <<= 1){
    unsigned add = (t >= o && t < 512) ? incl[t-o] : 0;
    __syncthreads();
    if (t < 512) incl[t] += add;
    __syncthreads();
  }
  if (t < 512){
    cur[t] = 0;
    int node = (b << BSH) + t;
    if (node < NN) rowptr[node] = (int)(cbase + incl[t] - h[t]);
  }
  __syncthreads();
  for (unsigned i = t; i < cnt; i += 1024){
    uint2 du = bdu[cbase+i];
    unsigned ld = du.x & 511;
    unsigned pos = atomicAdd(&cur[ld], 1);
    unsigned slot = cbase + (incl[ld] - h[ld]) + pos;
    float4 w = bw[cbase+i];
    csr_u[slot] = du.y;
    ewp2[slot] = w.x;
    ewpmuls[slot] = make_float2(w.y, w.z);
  }
}

// ---- MFMA GEMM: Y[nrows x 128] = Xb @ Wt^T, bf16 in, fp32 acc.
//      DOTS=1: fused s/d = acc.asrc/adst (conv). DOTS=2: fused mu/ls dots (interleaved cols).
template<bool OUTF32, int DOTS>
__global__ __launch_bounds__(256) void gemm_bf16(const unsigned short* __restrict__ Xb,
                                                 const unsigned short* __restrict__ Wt,
                                                 void* __restrict__ Y,
                                                 const float* __restrict__ bias, int nrows,
                                                 const float* __restrict__ va,
                                                 const float* __restrict__ vb,
                                                 const float* __restrict__ vc,
                                                 const float* __restrict__ vd,
                                                 float* __restrict__ sOut,
                                                 float* __restrict__ dOut){
  __shared__ uint4 As[128*16];   // 32 KB, XOR-swizzled chunks
  __shared__ uint4 Bs[128*16];   // 32 KB
  int t = threadIdx.x;
  int row0 = blockIdx.x * 128;
  #pragma unroll
  for (int p = 0; p < 8; p++){
    int idx = p*256 + t;
    int r = idx >> 4, cir = idx & 15;
    uint4 v = make_uint4(0,0,0,0);
    if (row0 + r < nrows) v = *(const uint4*)(Xb + ((size_t)(row0+r))*128 + cir*8);
    As[r*16 + (cir ^ (r & 7))] = v;
  }
  #pragma unroll
  for (int p = 0; p < 8; p++){
    int idx = p*256 + t;
    int r = idx >> 4, cir = idx & 15;
    Bs[r*16 + (cir ^ (r & 7))] = *(const uint4*)(Wt + (size_t)r*128 + cir*8);
  }
  __syncthreads();
  int w = t >> 6, l = t & 63;
  int lr = l & 15;
  int lk = l >> 4;
  const bf16x8* As8 = (const bf16x8*)As;
  const bf16x8* Bs8 = (const bf16x8*)Bs;
  f32x4 acc[2][8];
  f32x4 zero = {0.f, 0.f, 0.f, 0.f};
  #pragma unroll
  for (int m = 0; m < 2; m++)
    #pragma unroll
    for (int n = 0; n < 8; n++) acc[m][n] = zero;
  #pragma unroll
  for (int ks = 0; ks < 4; ks++){
    bf16x8 a0, a1, bf[8];
    { int r = w*32 + lr;      a0 = As8[r*16 + ((ks*4+lk) ^ (r&7))]; }
    { int r = w*32 + 16 + lr; a1 = As8[r*16 + ((ks*4+lk) ^ (r&7))]; }
    #pragma unroll
    for (int nt = 0; nt < 8; nt++){
      int r = nt*16 + lr;
      bf[nt] = Bs8[r*16 + ((ks*4+lk) ^ (r&7))];
    }
    #pragma unroll
    for (int nt = 0; nt < 8; nt++){
      acc[0][nt] = __builtin_amdgcn_mfma_f32_16x16x32_bf16(a0, bf[nt], acc[0][nt], 0, 0, 0);
      acc[1][nt] = __builtin_amdgcn_mfma_f32_16x16x32_bf16(a1, bf[nt], acc[1][nt], 0, 0, 0);
    }
  }
  // fused attention dots from fp32 accumulators (reduce over cols = 16-lane lr group)
  if constexpr (DOTS == 1){
    #pragma unroll
    for (int mt = 0; mt < 2; mt++){
      #pragma unroll
      for (int i = 0; i < 4; i++){
        float ps = 0.f, pd = 0.f;
        #pragma unroll
        for (int nt = 0; nt < 8; nt++){
          float av = acc[mt][nt][i];
          int col = nt*16 + lr;
          ps = fmaf(av, va[col], ps);
          pd = fmaf(av, vb[col], pd);
        }
        ps = grp_sum16(ps); pd = grp_sum16(pd);
        int r = row0 + w*32 + mt*16 + lk*4 + i;
        if (lr == 0 && r < nrows){ sOut[r] = ps; dOut[r] = pd; }
      }
    }
  }
  if constexpr (DOTS == 2){
    #pragma unroll
    for (int mt = 0; mt < 2; mt++){
      #pragma unroll
      for (int i = 0; i < 4; i++){
        float pmu = 0.f, pdm = 0.f, pls = 0.f, pdl = 0.f;
        #pragma unroll
        for (int nt = 0; nt < 8; nt++){
          float av = acc[mt][nt][i];
          int col = nt*16 + lr;
          int c = col >> 1;
          if (col & 1){ pls = fmaf(av, vc[c], pls); pdl = fmaf(av, vd[c], pdl); }
          else        { pmu = fmaf(av, va[c], pmu); pdm = fmaf(av, vb[c], pdm); }
        }
        pmu = grp_sum16(pmu); pdm = grp_sum16(pdm);
        pls = grp_sum16(pls); pdl = grp_sum16(pdl);
        int r = row0 + w*32 + mt*16 + lk*4 + i;
        if (lr == 0 && r < nrows){
          ((float2*)sOut)[r] = make_float2(pmu, pls);
          ((float2*)dOut)[r] = make_float2(pdm, pdl);
        }
      }
    }
  }
  #pragma unroll
  for (int mt = 0; mt < 2; mt++){
    int gr0 = row0 + w*32 + mt*16 + lk*4;
    #pragma unroll
    for (int nt = 0; nt < 8; nt++){
      int col = nt*16 + lr;
      float bv = OUTF32 ? bias[col] : 0.f;
      #pragma unroll
      for (int i = 0; i < 4; i++){
        int r = gr0 + i;
        if (r < nrows){
          float o = acc[mt][nt][i];
          if constexpr (OUTF32) ((float*)Y)[(size_t)r*128 + col] = o + bv;
          else ((unsigned short*)Y)[(size_t)r*128 + col] = f2bf(o);
        }
      }
    }
  }
}

// ---- conv aggregation: 32-lane groups (2 nodes/wave), uint2 (4 col) per lane,
//      always-8-deep gather (tail lanes carry w=0) ----
template<bool HAS_EW>
__global__ __launch_bounds__(256) void agg_conv(const unsigned short* __restrict__ Hb,
                                                const float* __restrict__ s,
                                                const float* __restrict__ dsc,
                                                const float* __restrict__ ewp,
                                                const int* __restrict__ rowptr,
                                                const unsigned* __restrict__ csr_u,
                                                const float* __restrict__ bias,
                                                const float* __restrict__ resid,
                                                unsigned short* __restrict__ out){
  int v = (blockIdx.x * blockDim.x + threadIdx.x) >> 5;
  int lig = threadIdx.x & 31;
  if (v >= NN) return;
  int rs = rowptr[v], re = rowptr[v+1];
  int deg = re - rs;
  float d_v = dsc[v];
  float acc[4] = {0.f,0.f,0.f,0.f};
  float pl = 0.f, ewl = 0.f;
  for (int base = rs; base < re; base += 32){
    int i = base + lig;
    int u = 0; float w = 0.f;
    if (i < re){
      u = (int)csr_u[i];
      float e = HAS_EW ? ewp[i] : 0.f;
      if (HAS_EW) ewl += e;
      float a = s[u] + d_v + e;
      float l = a > 0.f ? a : 0.2f*a;
      w = __expf(l);
    }
    pl += w;
    int nv = re - base; if (nv > 32) nv = 32;
    for (int j = 0; j < nv; j += 8){
      uint2 q[8]; float wj[8];
      #pragma unroll
      for (int k = 0; k < 8; k++){
        int uk = __shfl(u, j+k, 32);
        wj[k] = __shfl(w, j+k, 32);
        q[k] = *(const uint2*)(Hb + (size_t)uk*128 + lig*4);
      }
      #pragma unroll
      for (int k = 0; k < 8; k++){
        acc[0] = fmaf(wj[k], __uint_as_float(q[k].x << 16), acc[0]);
        acc[1] = fmaf(wj[k], __uint_as_float(q[k].x & 0xFFFF0000u), acc[1]);
        acc[2] = fmaf(wj[k], __uint_as_float(q[k].y << 16), acc[2]);
        acc[3] = fmaf(wj[k], __uint_as_float(q[k].y & 0xFFFF0000u), acc[3]);
      }
    }
  }
  float p = grp_sum32(pl);
  float ews = HAS_EW ? grp_sum32(ewl) : 0.f;
  float selfa = s[v] + d_v + (HAS_EW ? ews / (float)(deg > 1 ? deg : 1) : 0.f);
  float lself = selfa > 0.f ? selfa : 0.2f*selfa;
  float wself = __expf(lself);
  p += wself;
  {
    uint2 q = *(const uint2*)(Hb + (size_t)v*128 + lig*4);
    acc[0] = fmaf(wself, __uint_as_float(q.x << 16), acc[0]);
    acc[1] = fmaf(wself, __uint_as_float(q.x & 0xFFFF0000u), acc[1]);
    acc[2] = fmaf(wself, __uint_as_float(q.y << 16), acc[2]);
    acc[3] = fmaf(wself, __uint_as_float(q.y & 0xFFFF0000u), acc[3]);
  }
  float inv = 1.f / p;
  int c0 = lig*4;
  float4 bv = *(const float4*)(bias + c0);
  float o0 = fmaxf(acc[0]*inv + bv.x, 0.f);
  float o1 = fmaxf(acc[1]*inv + bv.y, 0.f);
  float o2 = fmaxf(acc[2]*inv + bv.z, 0.f);
  float o3 = fmaxf(acc[3]*inv + bv.w, 0.f);
  if (HAS_EW){
    float4 r0 = *(const float4*)(resid + (size_t)v*128 + c0);
    o0 += r0.x; o1 += r0.y; o2 += r0.z; o3 += r0.w;
  }
  uint2 ow;
  ow.x = (unsigned)f2bf(o0) | ((unsigned)f2bf(o1) << 16);
  ow.y = (unsigned)f2bf(o2) | ((unsigned)f2bf(o3) << 16);
  *(uint2*)(out + (size_t)v*128 + c0) = ow;
}

// ---- fused mu+ls aggregation: 32-lane groups, interleaved Y, always-8-deep ----
__global__ __launch_bounds__(256) void agg_muls(const unsigned short* __restrict__ Yb,
                                                const float2* __restrict__ sg,
                                                const float2* __restrict__ dg,
                                                const float2* __restrict__ ewpmuls,
                                                const int* __restrict__ rowptr,
                                                const unsigned* __restrict__ csr_u,
                                                const float* __restrict__ bmu,
                                                const float* __restrict__ bls,
                                                float* __restrict__ outmu,
                                                float* __restrict__ outls){
  int v = (blockIdx.x * blockDim.x + threadIdx.x) >> 5;
  int lig = threadIdx.x & 31;
  if (v >= NN) return;
  int rs = rowptr[v], re = rowptr[v+1];
  int deg = re - rs;
  float2 dv = dg[v];
  float accmu[2] = {0.f,0.f}, accls[2] = {0.f,0.f};
  float pmu = 0.f, pls = 0.f, ewlmu = 0.f, ewlls = 0.f;
  for (int base = rs; base < re; base += 32){
    int i = base + lig;
    int u = 0; float wmu = 0.f, wls = 0.f;
    if (i < re){
      u = (int)csr_u[i];
      float2 su = sg[u];
      float2 ee = ewpmuls[i];
      ewlmu += ee.x; ewlls += ee.y;
      float amu = su.x + dv.x + ee.x;
      float als = su.y + dv.y + ee.y;
      float lmu = amu > 0.f ? amu : 0.2f*amu;
      float lls = als > 0.f ? als : 0.2f*als;
      wmu = __expf(lmu); wls = __expf(lls);
    }
    pmu += wmu; pls += wls;
    int nv = re - base; if (nv > 32) nv = 32;
    for (int j = 0; j < nv; j += 8){
      uint2 q[8]; float wm[8], wl[8];
      #pragma unroll
      for (int k = 0; k < 8; k++){
        int uk = __shfl(u, j+k, 32);
        wm[k] = __shfl(wmu, j+k, 32);
        wl[k] = __shfl(wls, j+k, 32);
        q[k] = *(const uint2*)(Yb + (size_t)uk*128 + lig*4);
      }
      #pragma unroll
      for (int k = 0; k < 8; k++){
        accmu[0] = fmaf(wm[k], __uint_as_float(q[k].x << 16), accmu[0]);
        accls[0] = fmaf(wl[k], __uint_as_float(q[k].x & 0xFFFF0000u), accls[0]);
        accmu[1] = fmaf(wm[k], __uint_as_float(q[k].y << 16), accmu[1]);
        accls[1] = fmaf(wl[k], __uint_as_float(q[k].y & 0xFFFF0000u), accls[1]);
      }
    }
  }
  float Pmu = grp_sum32(pmu), Pls = grp_sum32(pls);
  float Emu = grp_sum32(ewlmu), Els = grp_sum32(ewlls);
  float2 sv = sg[v];
  float dnm = (float)(deg > 1 ? deg : 1);
  float selfmu = sv.x + dv.x + Emu/dnm;
  float selfls = sv.y + dv.y + Els/dnm;
  float lmu = selfmu > 0.f ? selfmu : 0.2f*selfmu;
  float lls = selfls > 0.f ? selfls : 0.2f*selfls;
  float wmu_s = __expf(lmu), wls_s = __expf(lls);
  Pmu += wmu_s; Pls += wls_s;
  {
    uint2 q = *(const uint2*)(Yb + (size_t)v*128 + lig*4);
    accmu[0] = fmaf(wmu_s, __uint_as_float(q.x << 16), accmu[0]);
    accls[0] = fmaf(wls_s, __uint_as_float(q.x & 0xFFFF0000u), accls[0]);
    accmu[1] = fmaf(wmu_s, __uint_as_float(q.y << 16), accmu[1]);
    accls[1] = fmaf(wls_s, __uint_as_float(q.y & 0xFFFF0000u), accls[1]);
  }
  float imu = 1.f/Pmu, ils = 1.f/Pls;
  int c0 = lig*2;
  float2 omu = make_float2(accmu[0]*imu + bmu[c0], accmu[1]*imu + bmu[c0+1]);
  float2 ols = make_float2(accls[0]*ils + bls[c0], accls[1]*ils + bls[c0+1]);
  *(float2*)(outmu + (size_t)v*64 + c0) = omu;
  *(float2*)(outls + (size_t)v*64 + c0) = ols;
}

extern "C" void kernel_launch(void* const* d_in, const int* in_sizes, int n_in,
                              void* d_out, int out_size, void* d_ws, size_t ws_size,
                              hipStream_t stream){
  const float* x    = (const float*)d_in[0];
  const int*   ei   = (const int*)  d_in[1];
  const float* ea   = (const float*)d_in[2];
  const float* W1   = (const float*)d_in[3];
  const float* a1s  = (const float*)d_in[4];
  const float* a1d  = (const float*)d_in[5];
  const float* b1   = (const float*)d_in[6];
  const float* W2   = (const float*)d_in[7];
  const float* a2s  = (const float*)d_in[8];
  const float* a2d  = (const float*)d_in[9];
  const float* b2   = (const float*)d_in[10];
  const float* We2  = (const float*)d_in[11];
  const float* ae2  = (const float*)d_in[12];
  const float* Wr   = (const float*)d_in[13];
  const float* br   = (const float*)d_in[14];
  const float* Wmu  = (const float*)d_in[15];
  const float* amus = (const float*)d_in[16];
  const float* amud = (const float*)d_in[17];
  const float* bmu  = (const float*)d_in[18];
  const float* Wemu = (const float*)d_in[19];
  const float* aemu = (const float*)d_in[20];
  const float* Wls  = (const float*)d_in[21];
  const float* alss = (const float*)d_in[22];
  const float* alsd = (const float*)d_in[23];
  const float* bls  = (const float*)d_in[24];
  const float* Wels = (const float*)d_in[25];
  const float* aels = (const float*)d_in[26];

  char* base = (char*)d_ws;
  size_t off = 0;
  auto alloc = [&](size_t bytes)->char*{
    char* p = base + off;
    off = (off + bytes + 511) & ~(size_t)511;
    return p;
  };
  int*      rowptr = (int*)   alloc((size_t)(NN+1)*4);
  unsigned* gbcnt  = (unsigned*)alloc(512*4);        // gbcnt[256] + gbfill[256]
  unsigned* gbfill = gbcnt + 256;
  unsigned* gbbase = (unsigned*)alloc(257*4);
  uint2*    bdu    = (uint2*) alloc((size_t)NE*8);
  float4*   bw     = (float4*)alloc((size_t)NE*16);
  unsigned* csr_u  = (unsigned*)alloc((size_t)NE*4);
  float*    ewp2   = (float*) alloc((size_t)NE*4);
  float2*   ewpmls = (float2*)alloc((size_t)NE*8);
  float*    wv     = (float*) alloc(48*4);
  float*    s1     = (float*) alloc((size_t)NN*4);
  float*    d1     = (float*) alloc((size_t)NN*4);
  float2*   sg2    = (float2*)alloc((size_t)NN*8);
  float2*   dg2    = (float2*)alloc((size_t)NN*8);
  unsigned short* W1t  = (unsigned short*)alloc(128*128*2);
  unsigned short* W2t  = (unsigned short*)alloc(128*128*2);
  unsigned short* Wrt  = (unsigned short*)alloc(128*128*2);
  unsigned short* Wmlt = (unsigned short*)alloc(128*128*2);
  unsigned short* Xb   = (unsigned short*)alloc((size_t)NN*128*2);
  unsigned short* bufA = (unsigned short*)alloc((size_t)NN*128*2);  // H1 -> H2 -> Y(muls)
  unsigned short* bufB = (unsigned short*)alloc((size_t)NN*128*2);  // h1 -> h
  if (off > ws_size) return;

  float* outF = (float*)d_out;   // XR (fp32 [NN][128]) then [mu | logstd]
  float* muO  = outF;
  float* lsO  = outF + (size_t)NN*64;

  const int HB   = (NE + 4095)/4096;    // 1024-thread, 4 edges/thread
  const int WB32 = (NN*32 + 255)/256;   // one 32-lane group per node
  const int GB   = (NN + 127)/128;
  const int CB   = (NN*128/8 + 255)/256;

  // precompute + graph build
  prep_w_kernel<<<4, 256, 0, stream>>>(W1, W2, Wr, Wmu, Wls, W1t, W2t, Wrt, Wmlt);
  wvec_kernel<<<1, 64, 0, stream>>>(We2, ae2, Wemu, aemu, Wels, aels, wv);
  cast_x_kernel<<<CB, 256, 0, stream>>>(x, Xb);
  zero_kernel<<<2, 256, 0, stream>>>((int*)gbcnt, 512);
  ehist_kernel<<<HB, 1024, 0, stream>>>(ei, gbcnt);
  bscan_kernel<<<1, 256, 0, stream>>>(gbcnt, gbbase, rowptr);
  bin_kernel<<<HB, 1024, 0, stream>>>(ei, ea, wv, gbbase, gbfill, bdu, bw);
  place_kernel<<<NBUK, 1024, 0, stream>>>(bdu, bw, gbbase, rowptr, csr_u, ewp2, ewpmls);

  // conv1 (dots fused into GEMM epilogue)
  gemm_bf16<false,1><<<GB, 256, 0, stream>>>(Xb, W1t, bufA, nullptr, NN,
                                             a1s, a1d, nullptr, nullptr, s1, d1);   // H1
  agg_conv<false><<<WB32, 256, 0, stream>>>(bufA, s1, d1, nullptr, rowptr, csr_u,
                                            b1, nullptr, bufB);                     // h1
  // conv2 + residual
  gemm_bf16<false,1><<<GB, 256, 0, stream>>>(bufB, W2t, bufA, nullptr, NN,
                                             a2s, a2d, nullptr, nullptr, s1, d1);   // H2
  gemm_bf16<true,0><<<GB, 256, 0, stream>>>(Xb, Wrt, outF, br, NN,
                                            nullptr, nullptr, nullptr, nullptr,
                                            nullptr, nullptr);                      // XR -> d_out
  agg_conv<true><<<WB32, 256, 0, stream>>>(bufA, s1, d1, ewp2, rowptr, csr_u,
                                           b2, outF, bufB);                         // h
  // mu + logstd (fused, interleaved; dots fused into GEMM)
  gemm_bf16<false,2><<<GB, 256, 0, stream>>>(bufB, Wmlt, bufA, nullptr, NN,
                                             amus, amud, alss, alsd,
                                             (float*)sg2, (float*)dg2);             // Y interleaved
  agg_muls<<<WB32, 256, 0, stream>>>(bufA, sg2, dg2, ewpmls, rowptr, csr_u,
                                     bmu, bls, muO, lsO);
}